// Round 2
// baseline (968.391 us; speedup 1.0000x reference)
//
#include <hip/hip_runtime.h>
#include <hip/hip_bf16.h>
#include <math.h>

#define B_SZ 2
#define SEQ  8192
#define DM   512
#define DI   1024
#define DS   16
#define DTR  32
#define M_TOT (B_SZ*SEQ)        // 16384 positions
#define LOG2E 1.44269504088896f
#define NCHUNK 64
#define CT     128              // chunk length (NCHUNK*CT == SEQ)
#define NCHAN  (4*DI*DS)        // 65536 scan channels ((dir*2+b)*DI+e)*DS+n
#define NG     (4*DI)           // 4096 (dir,b,e) groups

typedef __attribute__((ext_vector_type(8))) short bf16x8;
typedef __attribute__((ext_vector_type(4))) float f32x4;
typedef unsigned short u16;

__device__ __forceinline__ float bf2f(u16 u){
  union { unsigned u; float f; } v; v.u = ((unsigned)u) << 16; return v.f;
}
__device__ __forceinline__ u16 f2bf(float f){
  union { float f; unsigned u; } v; v.f = f;
  unsigned r = v.u + 0x7FFFu + ((v.u >> 16) & 1u);
  return (u16)(r >> 16);
}
__device__ __forceinline__ float silu_f(float x){ return x / (1.f + __expf(-x)); }
__device__ __forceinline__ float softplus_f(float x){
  return (x > 15.f) ? x : __logf(1.f + __expf(x));
}

// ---------------------------------------------------------------------------
// Templated MFMA bf16 GEMM: C[m,n] = sum_k A[m,k]*W[n,k]
//   A: f32 or bf16, row-major lda.  W: f32 (N,K) row-major, converted on load.
//   BM=128, BK=32, BN in {64,128}. 256 threads = 4 waves.
// EPI: 0 = split xz -> xpre(bf16), sz=silu (bf16)   (in_proj, N=2048)
//      1 = store bf16 (ldo)                          (xproj)
//      3 = store f32 (ldo)                           (out_proj)
// ---------------------------------------------------------------------------
template<int BN, int EPI, bool A_F32>
__global__ __launch_bounds__(256) void gemm_k(
    const void* __restrict__ Ap, int lda,
    const float* __restrict__ Bw, int K,
    void* __restrict__ out0, void* __restrict__ out1, int ldo)
{
  constexpr int BM = 128;
  constexpr int LS = 40;  // padded LDS row stride in shorts (80B)
  __shared__ __align__(16) short As[BM*LS];
  __shared__ __align__(16) short Bs[BN*LS];
  const int tid  = threadIdx.x;
  const int lane = tid & 63, wid = tid >> 6;
  const int mt = blockIdx.x, nt = blockIdx.y;

  constexpr int FM = (BN == 128) ? 4 : 2;
  const int wm = (BN == 128) ? ((wid >> 1) * 64) : (wid * 32);
  const int wn = (BN == 128) ? ((wid & 1) * 64) : 0;

  f32x4 acc[FM][4];
  #pragma unroll
  for (int i = 0; i < FM; i++)
    #pragma unroll
    for (int j = 0; j < 4; j++)
      acc[i][j] = (f32x4){0.f, 0.f, 0.f, 0.f};

  for (int k0 = 0; k0 < K; k0 += 32) {
    if (A_F32) {
      const float* A = (const float*)Ap;
      const int kg = tid & 7, rb = tid >> 3;
      #pragma unroll
      for (int i = 0; i < 4; i++) {
        const int r = rb + 32 * i;
        const float4 v = *(const float4*)(A + (size_t)(mt * BM + r) * lda + (k0 + kg * 4));
        short* d = &As[r * LS + kg * 4];
        d[0] = (short)f2bf(v.x); d[1] = (short)f2bf(v.y);
        d[2] = (short)f2bf(v.z); d[3] = (short)f2bf(v.w);
      }
    } else {
      const u16* A = (const u16*)Ap;
      const int kg = tid & 3, rb = tid >> 2;
      #pragma unroll
      for (int i = 0; i < 2; i++) {
        const int r = rb + 64 * i;
        const uint4 v = *(const uint4*)(A + (size_t)(mt * BM + r) * lda + (k0 + kg * 8));
        *(uint4*)&As[r * LS + kg * 8] = v;
      }
    }
    {
      const int kg = tid & 7, rb = tid >> 3;
      #pragma unroll
      for (int i = 0; i < BN / 32; i++) {
        const int r = rb + 32 * i;
        const float4 v = *(const float4*)(Bw + (size_t)(nt * BN + r) * K + (k0 + kg * 4));
        short* d = &Bs[r * LS + kg * 4];
        d[0] = (short)f2bf(v.x); d[1] = (short)f2bf(v.y);
        d[2] = (short)f2bf(v.z); d[3] = (short)f2bf(v.w);
      }
    }
    __syncthreads();
    const int row = lane & 15, kq = (lane >> 4) * 8;
    bf16x8 af[FM], bfr[4];
    #pragma unroll
    for (int i = 0; i < FM; i++) af[i] = *(const bf16x8*)&As[(wm + i * 16 + row) * LS + kq];
    #pragma unroll
    for (int j = 0; j < 4; j++)  bfr[j] = *(const bf16x8*)&Bs[(wn + j * 16 + row) * LS + kq];
    #pragma unroll
    for (int i = 0; i < FM; i++)
      #pragma unroll
      for (int j = 0; j < 4; j++)
        acc[i][j] = __builtin_amdgcn_mfma_f32_16x16x32_bf16(af[i], bfr[j], acc[i][j], 0, 0, 0);
    __syncthreads();
  }

  const int rb4 = (lane >> 4) * 4, col = lane & 15;
  #pragma unroll
  for (int i = 0; i < FM; i++) {
    #pragma unroll
    for (int j = 0; j < 4; j++) {
      #pragma unroll
      for (int r = 0; r < 4; r++) {
        const int m = mt * BM + wm + i * 16 + rb4 + r;
        const int n = nt * BN + wn + j * 16 + col;
        const float v = acc[i][j][r];
        if (EPI == 0) {
          if (n < DI) ((u16*)out0)[(size_t)m * DI + n] = f2bf(v);
          else        ((u16*)out1)[(size_t)m * DI + (n - DI)] = f2bf(silu_f(v));
        } else if (EPI == 1) {
          ((u16*)out0)[(size_t)m * ldo + n] = f2bf(v);
        } else {
          ((float*)out0)[(size_t)m * ldo + n] = v;
        }
      }
    }
  }
}

// ---------------------------------------------------------------------------
// Depthwise causal conv(4) + bias + silu, both directions.
// dir r consumes x_pre in reversed time order and emits x_r in reversed order.
// grid: (64 l-tiles of 128, b + 2*dir)
// ---------------------------------------------------------------------------
__global__ __launch_bounds__(256) void conv_k(
    const u16* __restrict__ xpre,
    const float* __restrict__ wf, const float* __restrict__ bf_,
    const float* __restrict__ wr, const float* __restrict__ br_,
    u16* __restrict__ xf, u16* __restrict__ xr)
{
  const int lt  = blockIdx.x;
  const int b   = blockIdx.y & 1;
  const int dir = blockIdx.y >> 1;
  const int tid = threadIdx.x;
  const float* w  = dir ? wr : wf;
  const float* bb = dir ? br_ : bf_;
  u16* xo = dir ? xr : xf;
  const int l0 = lt * 128;
  for (int j = 0; j < 4; j++) {
    const int e = j * 256 + tid;
    const float w0 = w[e*4+0], w1 = w[e*4+1], w2 = w[e*4+2], w3 = w[e*4+3], bv = bb[e];
    const size_t base = (size_t)b * SEQ * DI + e;
    auto load = [&](int q) -> float {
      if (q < 0) return 0.f;
      const int li = dir ? (SEQ - 1 - q) : q;
      return bf2f(xpre[base + (size_t)li * DI]);
    };
    float h0 = load(l0 - 3), h1 = load(l0 - 2), h2 = load(l0 - 1);
    for (int l = l0; l < l0 + 128; l++) {
      const float h3 = load(l);
      const float v = bv + w0*h0 + w1*h1 + w2*h2 + w3*h3;
      xo[base + (size_t)l * DI] = f2bf(silu_f(v));
      h0 = h1; h1 = h2; h2 = h3;
    }
  }
}

// ---------------------------------------------------------------------------
// Scan pass A: per (dir,b,chunk,e): chunk-local scan from h=0.
// delta computed on the fly: softplus(dot(xdbl[m,:32], dtw[e,:]) + dtb[e]).
// Writes: bP[c][chan] = partial h, sumdP[c][g] = sum_t delta.
// grid: (4 e-blocks, 64 chunks, 2 b); launched per dir.
// ---------------------------------------------------------------------------
__global__ __launch_bounds__(256) void scanA_k(
    const u16* __restrict__ xdbl, const u16* __restrict__ x,
    const float* __restrict__ A_log,
    const float* __restrict__ dtw, const float* __restrict__ dtb,
    float* __restrict__ sumdP, float* __restrict__ bP, int dir)
{
  const int e = blockIdx.x * 256 + threadIdx.x;
  const int c = blockIdx.y;
  const int b = blockIdx.z;
  float A2[DS], h[DS], dw[DTR];
  #pragma unroll
  for (int n = 0; n < DS; n++) { A2[n] = -__expf(A_log[e * DS + n]) * LOG2E; h[n] = 0.f; }
  #pragma unroll
  for (int r = 0; r < DTR; r += 4) {
    const float4 v = *(const float4*)(dtw + e * DTR + r);
    dw[r] = v.x; dw[r+1] = v.y; dw[r+2] = v.z; dw[r+3] = v.w;
  }
  const float bias = dtb[e];
  float sumd = 0.f;
  const size_t m0 = (size_t)b * SEQ + (size_t)c * CT;
  for (int t = 0; t < CT; t++) {
    const size_t m = m0 + t;
    union { uint4 v[4]; u16 s[32]; } DT;
    #pragma unroll
    for (int q = 0; q < 4; q++) DT.v[q] = ((const uint4*)(xdbl + m * 64))[q];
    union { uint4 v[2]; u16 s[16]; } Bv;
    Bv.v[0] = ((const uint4*)(xdbl + m * 64 + 32))[0];
    Bv.v[1] = ((const uint4*)(xdbl + m * 64 + 32))[1];
    float dot = bias;
    #pragma unroll
    for (int r = 0; r < DTR; r++) dot += bf2f(DT.s[r]) * dw[r];
    const float d = softplus_f(dot);
    const float xv  = bf2f(x[m * DI + e]);
    const float dbx = d * xv;
    sumd += d;
    #pragma unroll
    for (int n = 0; n < DS; n++) {
      const float dA = exp2f(A2[n] * d);
      h[n] = dA * h[n] + dbx * bf2f(Bv.s[n]);
    }
  }
  const int g = (dir * 2 + b) * DI + e;
  const size_t cb = (size_t)c * NCHAN + (size_t)g * DS;
  #pragma unroll
  for (int n = 0; n < DS; n++) bP[cb + n] = h[n];
  sumdP[(size_t)c * NG + g] = sumd;
}

// Scan pass B: cross-chunk scan, in place (bP becomes h_in per chunk).
// a = exp2(A2 * sumd) recomputed from A_log (exact same math as pass A).
__global__ __launch_bounds__(256) void scanB_k(
    const float* __restrict__ sumdP, float* __restrict__ bP,
    const float* __restrict__ Alog_f, const float* __restrict__ Alog_r)
{
  const int ch = blockIdx.x * 256 + threadIdx.x;   // 0..65535
  const int g = ch >> 4, n = ch & 15;
  const int dir = g >> 11, e = g & (DI - 1);
  const float* Al = dir ? Alog_r : Alog_f;
  const float A2 = -__expf(Al[e * DS + n]) * LOG2E;
  float h = 0.f;
  for (int c = 0; c < NCHUNK; c++) {
    const float a = exp2f(A2 * sumdP[(size_t)c * NG + g]);
    const size_t i = (size_t)c * NCHAN + ch;
    const float bb = bP[i];
    bP[i] = h;              // h_in for chunk c
    h = a * h + bb;
  }
}

// Scan pass C: replay chunk from h_in, emit y.
// DIR==0: Yf[m] = bf16(y + x*D)   -- Yf aliases x (in-place, same index)
// DIR==1: Yb[mo] = bf16((Yf[mo] + y + x*D) * sz[mo]),  mo = flipped index
template<int DIR>
__global__ __launch_bounds__(256) void scanC_k(
    const u16* __restrict__ xdbl, const u16* __restrict__ x,
    const float* __restrict__ A_log,
    const float* __restrict__ dtw, const float* __restrict__ dtb,
    const float* __restrict__ Dsk, const float* __restrict__ hin,
    u16* __restrict__ Yf, u16* __restrict__ Yb, const u16* __restrict__ sz)
{
  const int e = blockIdx.x * 256 + threadIdx.x;
  const int c = blockIdx.y;
  const int b = blockIdx.z;
  float A2[DS], h[DS], dw[DTR];
  #pragma unroll
  for (int n = 0; n < DS; n++) A2[n] = -__expf(A_log[e * DS + n]) * LOG2E;
  #pragma unroll
  for (int r = 0; r < DTR; r += 4) {
    const float4 v = *(const float4*)(dtw + e * DTR + r);
    dw[r] = v.x; dw[r+1] = v.y; dw[r+2] = v.z; dw[r+3] = v.w;
  }
  const float bias = dtb[e];
  const float dskip = Dsk[e];
  const int g = (DIR * 2 + b) * DI + e;
  const size_t cb = (size_t)c * NCHAN + (size_t)g * DS;
  #pragma unroll
  for (int n = 0; n < DS; n++) h[n] = hin[cb + n];
  const size_t m0 = (size_t)b * SEQ + (size_t)c * CT;
  for (int t = 0; t < CT; t++) {
    const size_t m = m0 + t;
    union { uint4 v[4]; u16 s[32]; } DT;
    #pragma unroll
    for (int q = 0; q < 4; q++) DT.v[q] = ((const uint4*)(xdbl + m * 64))[q];
    union { uint4 v[4]; u16 s[32]; } BC;
    #pragma unroll
    for (int q = 0; q < 4; q++) BC.v[q] = ((const uint4*)(xdbl + m * 64 + 32))[q];
    float dot = bias;
    #pragma unroll
    for (int r = 0; r < DTR; r++) dot += bf2f(DT.s[r]) * dw[r];
    const float d = softplus_f(dot);
    const float xv  = bf2f(x[m * DI + e]);
    const float dbx = d * xv;
    float y = 0.f;
    #pragma unroll
    for (int n = 0; n < DS; n++) {
      const float dA = exp2f(A2[n] * d);
      h[n] = dA * h[n] + dbx * bf2f(BC.s[n]);
      y += h[n] * bf2f(BC.s[16 + n]);
    }
    if (DIR == 0) {
      Yf[m * DI + e] = f2bf(y + xv * dskip);   // in-place over x (same addr)
    } else {
      const int p = (int)(c * CT + t);
      const size_t mo = (size_t)b * SEQ + (SEQ - 1 - p);
      const float tot = (bf2f(Yf[mo * DI + e]) + y + xv * dskip) * bf2f(sz[mo * DI + e]);
      Yb[mo * DI + e] = f2bf(tot);
    }
  }
}

// ---------------------------------------------------------------------------
extern "C" void kernel_launch(void* const* d_in, const int* in_sizes, int n_in,
                              void* d_out, int out_size, void* d_ws, size_t ws_size,
                              hipStream_t stream)
{
  (void)in_sizes; (void)n_in; (void)out_size; (void)ws_size;
  const float* u      = (const float*)d_in[0];
  const float* in_w   = (const float*)d_in[1];
  const float* out_w  = (const float*)d_in[2];
  const float* cw_f   = (const float*)d_in[3];
  const float* cb_f   = (const float*)d_in[4];
  const float* xw_f   = (const float*)d_in[5];
  const float* dtw_f  = (const float*)d_in[6];
  const float* dtb_f  = (const float*)d_in[7];
  const float* Alog_f = (const float*)d_in[8];
  const float* D_f    = (const float*)d_in[9];
  const float* cw_r   = (const float*)d_in[10];
  const float* cb_r   = (const float*)d_in[11];
  const float* xw_r   = (const float*)d_in[12];
  const float* dtw_r  = (const float*)d_in[13];
  const float* dtb_r  = (const float*)d_in[14];
  const float* Alog_r = (const float*)d_in[15];
  const float* D_r    = (const float*)d_in[16];

  char* ws = (char*)d_ws;
  size_t off = 0;
  auto alloc = [&](size_t bytes) -> void* {
    void* p = ws + off;
    off += (bytes + 255) & ~(size_t)255;
    return p;
  };
  const size_t mexe = (size_t)M_TOT * DI;          // 16.78M elements
  // Total workspace: 33.55*3 + 2.1*2 + 1.05 + 16.78 = 122.7 MB
  u16*   xpre  = (u16*)alloc(mexe * 2);            // bf16; dead after conv -> Yb
  u16*   xf    = (u16*)alloc(mexe * 2);            // x_f; overwritten in place by Yf
  u16*   xr    = (u16*)alloc(mexe * 2);
  u16*   xdblf = (u16*)alloc((size_t)M_TOT * 64 * 2);
  u16*   xdblr = (u16*)alloc((size_t)M_TOT * 64 * 2);
  float* sumdP = (float*)alloc((size_t)NCHUNK * NG * 4);
  float* bP    = (float*)alloc((size_t)NCHUNK * NCHAN * 4);
  u16*   szb   = (u16*)d_out;                      // silu(z) lives in d_out (dead before out_proj)
  u16*   Yf    = xf;                               // in-place
  u16*   Yb    = xpre;                             // reuse

  dim3 blk(256);
  // 1) in_proj: xz = u @ in_w^T ; split -> xpre(bf16), sz=silu(z) in d_out
  gemm_k<128, 0, true ><<<dim3(128, 16), blk, 0, stream>>>(u, DM, in_w, DM, xpre, szb, 0);
  // 2) depthwise conv + silu, both dirs (dir r in reversed order)
  conv_k<<<dim3(64, 4), blk, 0, stream>>>(xpre, cw_f, cb_f, cw_r, cb_r, xf, xr);
  // 3) xproj: xdbl = x @ xproj_w^T   (M x 64, K=1024)
  gemm_k<64, 1, false><<<dim3(128, 1), blk, 0, stream>>>(xf, DI, xw_f, DI, xdblf, nullptr, 64);
  gemm_k<64, 1, false><<<dim3(128, 1), blk, 0, stream>>>(xr, DI, xw_r, DI, xdblr, nullptr, 64);
  // 4) chunked scan (delta computed on the fly from xdbl + dtw/dtb)
  scanA_k<<<dim3(4, NCHUNK, 2), blk, 0, stream>>>(xdblf, xf, Alog_f, dtw_f, dtb_f, sumdP, bP, 0);
  scanA_k<<<dim3(4, NCHUNK, 2), blk, 0, stream>>>(xdblr, xr, Alog_r, dtw_r, dtb_r, sumdP, bP, 1);
  scanB_k<<<dim3(NCHAN / 256), blk, 0, stream>>>(sumdP, bP, Alog_f, Alog_r);
  scanC_k<0><<<dim3(4, NCHUNK, 2), blk, 0, stream>>>(xdblf, xf, Alog_f, dtw_f, dtb_f, D_f, bP, Yf, nullptr, nullptr);
  scanC_k<1><<<dim3(4, NCHUNK, 2), blk, 0, stream>>>(xdblr, xr, Alog_r, dtw_r, dtb_r, D_r, bP, Yf, Yb, szb);
  // 5) out_proj: out = Yb @ out_w^T  (f32 out)
  gemm_k<128, 3, false><<<dim3(128, 4), blk, 0, stream>>>(Yb, DI, out_w, DI, d_out, nullptr, DM);
}

// Round 3
// 506.516 us; speedup vs baseline: 1.9119x; 1.9119x over previous
//
#include <hip/hip_runtime.h>
#include <hip/hip_bf16.h>
#include <math.h>

#define B_SZ 2
#define SEQ  8192
#define DM   512
#define DI   1024
#define DS   16
#define DTR  32
#define M_TOT (B_SZ*SEQ)        // 16384 positions
#define LOG2E 1.44269504088896f
#define NCHAN  (4*DI*DS)        // 65536 scan channels ((dir*2+b)*DI+e)*DS+n
#define NG     (4*DI)           // 4096 (dir,b,e) groups

typedef __attribute__((ext_vector_type(8))) short bf16x8;
typedef __attribute__((ext_vector_type(4))) float f32x4;
typedef unsigned short u16;

struct TrueT  { static constexpr bool value = true;  };
struct FalseT { static constexpr bool value = false; };

__device__ __forceinline__ float bf2f(u16 u){
  union { unsigned u; float f; } v; v.u = ((unsigned)u) << 16; return v.f;
}
__device__ __forceinline__ u16 f2bf(float f){
  union { float f; unsigned u; } v; v.f = f;
  unsigned r = v.u + 0x7FFFu + ((v.u >> 16) & 1u);
  return (u16)(r >> 16);
}
__device__ __forceinline__ float silu_f(float x){ return x / (1.f + __expf(-x)); }
__device__ __forceinline__ float softplus_f(float x){
  return (x > 15.f) ? x : __logf(1.f + __expf(x));
}

// dA[n] = exp2(A2[n]*d); structured fast path uses dA[n] = q^(n+1), q=exp2(A20*d)
template<bool S>
__device__ __forceinline__ void dA_calc(float d, const float* A2, float A20, float* dAv){
  if (S) {
    const float q = exp2f(A20 * d);
    dAv[0]  = q;
    dAv[1]  = q * q;
    dAv[2]  = dAv[1] * q;
    dAv[3]  = dAv[1] * dAv[1];
    dAv[4]  = dAv[3] * q;
    dAv[5]  = dAv[3] * dAv[1];
    dAv[6]  = dAv[3] * dAv[2];
    dAv[7]  = dAv[3] * dAv[3];
    dAv[8]  = dAv[7] * q;
    dAv[9]  = dAv[7] * dAv[1];
    dAv[10] = dAv[7] * dAv[2];
    dAv[11] = dAv[7] * dAv[3];
    dAv[12] = dAv[7] * dAv[4];
    dAv[13] = dAv[7] * dAv[5];
    dAv[14] = dAv[7] * dAv[6];
    dAv[15] = dAv[7] * dAv[7];
  } else {
    #pragma unroll
    for (int n = 0; n < DS; n++) dAv[n] = exp2f(A2[n] * d);
  }
}

// ---------------------------------------------------------------------------
// Templated MFMA bf16 GEMM: C[m,n] = sum_k A[m,k]*W[n,k]
// EPI: 0 = split xz -> out0(bf16), out1=silu (bf16)   (in_proj, N=2048)
//      1 = store bf16 (ldo)                            (xproj)
//      2 = softplus(acc + bias[n]) -> bf16 (ldo)       (delta proj)
//      3 = store f32 (ldo)                             (out_proj)
// DUAL: blockIdx.z selects pointer set (merged fwd/rev launches)
// ---------------------------------------------------------------------------
template<int BN, int EPI, bool A_F32, bool DUAL>
__global__ __launch_bounds__(256) void gemm_k(
    const void* __restrict__ Ap,  const void* __restrict__ Ap2, int lda,
    const float* __restrict__ Bw, const float* __restrict__ Bw2, int K,
    void* __restrict__ out0, void* __restrict__ out02,
    void* __restrict__ out1,
    const float* __restrict__ bias, const float* __restrict__ bias2, int ldo)
{
  constexpr int BM = 128;
  constexpr int LS = 40;  // padded LDS row stride in shorts (80B)
  __shared__ __align__(16) short As[BM*LS];
  __shared__ __align__(16) short Bs[BN*LS];
  const int tid  = threadIdx.x;
  const int lane = tid & 63, wid = tid >> 6;
  const int mt = blockIdx.x, nt = blockIdx.y;
  const int z  = DUAL ? blockIdx.z : 0;
  const void*  ApS = z ? Ap2 : Ap;
  const float* BwS = z ? Bw2 : Bw;
  void* o0 = z ? out02 : out0;
  const float* bi = z ? bias2 : bias;

  constexpr int FM = (BN == 128) ? 4 : 2;
  const int wm = (BN == 128) ? ((wid >> 1) * 64) : (wid * 32);
  const int wn = (BN == 128) ? ((wid & 1) * 64) : 0;

  f32x4 acc[FM][4];
  #pragma unroll
  for (int i = 0; i < FM; i++)
    #pragma unroll
    for (int j = 0; j < 4; j++)
      acc[i][j] = (f32x4){0.f, 0.f, 0.f, 0.f};

  for (int k0 = 0; k0 < K; k0 += 32) {
    if (A_F32) {
      const float* A = (const float*)ApS;
      const int kg = tid & 7, rb = tid >> 3;
      #pragma unroll
      for (int i = 0; i < 4; i++) {
        const int r = rb + 32 * i;
        const float4 v = *(const float4*)(A + (size_t)(mt * BM + r) * lda + (k0 + kg * 4));
        short* d = &As[r * LS + kg * 4];
        d[0] = (short)f2bf(v.x); d[1] = (short)f2bf(v.y);
        d[2] = (short)f2bf(v.z); d[3] = (short)f2bf(v.w);
      }
    } else {
      const u16* A = (const u16*)ApS;
      const int kg = tid & 3, rb = tid >> 2;
      #pragma unroll
      for (int i = 0; i < 2; i++) {
        const int r = rb + 64 * i;
        const uint4 v = *(const uint4*)(A + (size_t)(mt * BM + r) * lda + (k0 + kg * 8));
        *(uint4*)&As[r * LS + kg * 8] = v;
      }
    }
    {
      const int kg = tid & 7, rb = tid >> 3;
      #pragma unroll
      for (int i = 0; i < BN / 32; i++) {
        const int r = rb + 32 * i;
        const float4 v = *(const float4*)(BwS + (size_t)(nt * BN + r) * K + (k0 + kg * 4));
        short* d = &Bs[r * LS + kg * 4];
        d[0] = (short)f2bf(v.x); d[1] = (short)f2bf(v.y);
        d[2] = (short)f2bf(v.z); d[3] = (short)f2bf(v.w);
      }
    }
    __syncthreads();
    const int row = lane & 15, kq = (lane >> 4) * 8;
    bf16x8 af[FM], bfr[4];
    #pragma unroll
    for (int i = 0; i < FM; i++) af[i] = *(const bf16x8*)&As[(wm + i * 16 + row) * LS + kq];
    #pragma unroll
    for (int j = 0; j < 4; j++)  bfr[j] = *(const bf16x8*)&Bs[(wn + j * 16 + row) * LS + kq];
    #pragma unroll
    for (int i = 0; i < FM; i++)
      #pragma unroll
      for (int j = 0; j < 4; j++)
        acc[i][j] = __builtin_amdgcn_mfma_f32_16x16x32_bf16(af[i], bfr[j], acc[i][j], 0, 0, 0);
    __syncthreads();
  }

  const int rb4 = (lane >> 4) * 4, col = lane & 15;
  #pragma unroll
  for (int i = 0; i < FM; i++) {
    #pragma unroll
    for (int j = 0; j < 4; j++) {
      #pragma unroll
      for (int r = 0; r < 4; r++) {
        const int m = mt * BM + wm + i * 16 + rb4 + r;
        const int n = nt * BN + wn + j * 16 + col;
        const float v = acc[i][j][r];
        if (EPI == 0) {
          if (n < DI) ((u16*)o0)[(size_t)m * DI + n] = f2bf(v);
          else        ((u16*)out1)[(size_t)m * DI + (n - DI)] = f2bf(silu_f(v));
        } else if (EPI == 1) {
          ((u16*)o0)[(size_t)m * ldo + n] = f2bf(v);
        } else if (EPI == 2) {
          ((u16*)o0)[(size_t)m * ldo + n] = f2bf(softplus_f(v + bi[n]));
        } else {
          ((float*)o0)[(size_t)m * ldo + n] = v;
        }
      }
    }
  }
}

// ---------------------------------------------------------------------------
// Depthwise causal conv(4) + bias + silu, both directions.
// grid: (128 l-tiles of 64, b + 2*dir)
// ---------------------------------------------------------------------------
__global__ __launch_bounds__(256) void conv_k(
    const u16* __restrict__ xpre,
    const float* __restrict__ wf, const float* __restrict__ bf_,
    const float* __restrict__ wr, const float* __restrict__ br_,
    u16* __restrict__ xf, u16* __restrict__ xr)
{
  const int lt  = blockIdx.x;
  const int b   = blockIdx.y & 1;
  const int dir = blockIdx.y >> 1;
  const int tid = threadIdx.x;
  const float* w  = dir ? wr : wf;
  const float* bb = dir ? br_ : bf_;
  u16* xo = dir ? xr : xf;
  const int l0 = lt * 64;
  for (int j = 0; j < 4; j++) {
    const int e = j * 256 + tid;
    const float w0 = w[e*4+0], w1 = w[e*4+1], w2 = w[e*4+2], w3 = w[e*4+3], bv = bb[e];
    const size_t base = (size_t)b * SEQ * DI + e;
    auto load = [&](int q) -> float {
      if (q < 0) return 0.f;
      const int li = dir ? (SEQ - 1 - q) : q;
      return bf2f(xpre[base + (size_t)li * DI]);
    };
    float h0 = load(l0 - 3), h1 = load(l0 - 2), h2 = load(l0 - 1);
    for (int l = l0; l < l0 + 64; l++) {
      const float h3 = load(l);
      const float v = bv + w0*h0 + w1*h1 + w2*h2 + w3*h3;
      xo[base + (size_t)l * DI] = f2bf(silu_f(v));
      h0 = h1; h1 = h2; h2 = h3;
    }
  }
}

// ---------------------------------------------------------------------------
// Scan pass A (merged dirs): per (dir,b,chunk,e) chunk-local scan from h=0.
// PRE: delta precomputed (bf16). Otherwise on-the-fly (4-acc dot + softplus).
// grid: (4 e-blocks, nchunk, 4=dir*2+b)
// ---------------------------------------------------------------------------
template<bool PRE>
__global__ __launch_bounds__(256) void scanA_k(
    const u16* __restrict__ xdblf_, const u16* __restrict__ xdblr_,
    const u16* __restrict__ xf_,    const u16* __restrict__ xr_,
    const float* __restrict__ Alf,  const float* __restrict__ Alr,
    const float* __restrict__ dtwf, const float* __restrict__ dtwr,
    const float* __restrict__ dtbf, const float* __restrict__ dtbr,
    const u16* __restrict__ df_,    const u16* __restrict__ dr_,
    float* __restrict__ sumdP, float* __restrict__ bP, int ct)
{
  const int e = blockIdx.x * 256 + threadIdx.x;
  const int c = blockIdx.y;
  const int dir = blockIdx.z >> 1, b = blockIdx.z & 1;
  const u16* xdbl = dir ? xdblr_ : xdblf_;
  const u16* x    = dir ? xr_ : xf_;
  const float* Al = dir ? Alr : Alf;
  const u16* dpre = dir ? dr_ : df_;

  float A2[DS], h[DS], dw[DTR];
  #pragma unroll
  for (int n = 0; n < DS; n++) { A2[n] = -__expf(Al[e * DS + n]) * LOG2E; h[n] = 0.f; }
  const float A20 = A2[0];
  bool structured = true;
  #pragma unroll
  for (int n = 1; n < DS; n++)
    structured = structured && (fabsf(A2[n] - (float)(n + 1) * A20) <= 1e-3f * fabsf(A2[n]));

  float bias = 0.f;
  if (!PRE) {
    const float* dtw = dir ? dtwr : dtwf;
    #pragma unroll
    for (int r = 0; r < DTR; r += 4) {
      const float4 v = *(const float4*)(dtw + e * DTR + r);
      dw[r] = v.x; dw[r+1] = v.y; dw[r+2] = v.z; dw[r+3] = v.w;
    }
    bias = (dir ? dtbr : dtbf)[e];
  }

  float sumd = 0.f;
  const size_t m0 = (size_t)b * SEQ + (size_t)c * ct;

  auto core = [&](auto sc) {
    constexpr bool S = decltype(sc)::value;
    for (int t = 0; t < ct; t++) {
      const size_t m = m0 + t;
      float d;
      if (PRE) {
        d = bf2f(dpre[m * DI + e]);
      } else {
        union { uint4 v[4]; u16 s[32]; } DT;
        #pragma unroll
        for (int q = 0; q < 4; q++) DT.v[q] = ((const uint4*)(xdbl + m * 64))[q];
        float a0 = 0.f, a1 = 0.f, a2 = 0.f, a3 = 0.f;
        #pragma unroll
        for (int r = 0; r < DTR; r += 4) {
          a0 += bf2f(DT.s[r+0]) * dw[r+0];
          a1 += bf2f(DT.s[r+1]) * dw[r+1];
          a2 += bf2f(DT.s[r+2]) * dw[r+2];
          a3 += bf2f(DT.s[r+3]) * dw[r+3];
        }
        d = softplus_f(((a0 + a1) + (a2 + a3)) + bias);
      }
      const float xv  = bf2f(x[m * DI + e]);
      const float dbx = d * xv;
      sumd += d;
      union { uint4 v[2]; u16 s[16]; } Bv;
      Bv.v[0] = ((const uint4*)(xdbl + m * 64 + 32))[0];
      Bv.v[1] = ((const uint4*)(xdbl + m * 64 + 32))[1];
      float dAv[DS];
      dA_calc<S>(d, A2, A20, dAv);
      #pragma unroll
      for (int n = 0; n < DS; n++)
        h[n] = dAv[n] * h[n] + dbx * bf2f(Bv.s[n]);
    }
  };
  if (structured) core(TrueT{}); else core(FalseT{});

  const int g = (dir * 2 + b) * DI + e;
  const size_t cb = (size_t)c * NCHAN + (size_t)g * DS;
  #pragma unroll
  for (int n = 0; n < DS; n++) bP[cb + n] = h[n];
  sumdP[(size_t)c * NG + g] = sumd;
}

// Scan pass B: cross-chunk scan, in place (bP becomes h_in per chunk).
__global__ __launch_bounds__(256) void scanB_k(
    const float* __restrict__ sumdP, float* __restrict__ bP,
    const float* __restrict__ Alog_f, const float* __restrict__ Alog_r, int nchunk)
{
  const int ch = blockIdx.x * 256 + threadIdx.x;   // 0..65535
  const int g = ch >> 4, n = ch & 15;
  const int dir = g >> 11, e = g & (DI - 1);
  const float* Al = dir ? Alog_r : Alog_f;
  const float A2 = -__expf(Al[e * DS + n]) * LOG2E;
  float h = 0.f;
  for (int c = 0; c < nchunk; c++) {
    const float a = exp2f(A2 * sumdP[(size_t)c * NG + g]);
    const size_t i = (size_t)c * NCHAN + ch;
    const float bb = bP[i];
    bP[i] = h;              // h_in for chunk c
    h = a * h + bb;
  }
}

// ---------------------------------------------------------------------------
// Scan pass C: replay chunk from h_in, emit y (+ x*D).
// MODE 0: merged dirs (z=dir*2+b). dir0 -> yf[m] (in place over x_f);
//         dir1 -> yr[mo] (mo = flipped). No sz/Yf read.
// MODE 1: legacy dir0 only (z=b): yf[m] = y + x*D
// MODE 2: legacy dir1 combine (z=b): yr[mo] = (yf[mo] + y + x*D) * sz[mo]
// ---------------------------------------------------------------------------
template<bool PRE, int MODE>
__global__ __launch_bounds__(256) void scanC_k(
    const u16* __restrict__ xdblf_, const u16* __restrict__ xdblr_,
    const u16* __restrict__ xf_,    const u16* __restrict__ xr_,
    const float* __restrict__ Alf,  const float* __restrict__ Alr,
    const float* __restrict__ dtwf, const float* __restrict__ dtwr,
    const float* __restrict__ dtbf, const float* __restrict__ dtbr,
    const u16* __restrict__ df_,    const u16* __restrict__ dr_,
    const float* __restrict__ Dskf, const float* __restrict__ Dskr,
    const float* __restrict__ hin,
    u16* __restrict__ yf, u16* __restrict__ yr,
    const u16* __restrict__ szp, int ct)
{
  const int e = blockIdx.x * 256 + threadIdx.x;
  const int c = blockIdx.y;
  int dir, b;
  if (MODE == 0) { dir = blockIdx.z >> 1; b = blockIdx.z & 1; }
  else           { dir = (MODE == 2);     b = blockIdx.z; }
  const u16* xdbl = dir ? xdblr_ : xdblf_;
  const u16* x    = dir ? xr_ : xf_;
  const float* Al = dir ? Alr : Alf;
  const u16* dpre = dir ? dr_ : df_;
  const float dskip = (dir ? Dskr : Dskf)[e];

  float A2[DS], h[DS], dw[DTR];
  #pragma unroll
  for (int n = 0; n < DS; n++) A2[n] = -__expf(Al[e * DS + n]) * LOG2E;
  const float A20 = A2[0];
  bool structured = true;
  #pragma unroll
  for (int n = 1; n < DS; n++)
    structured = structured && (fabsf(A2[n] - (float)(n + 1) * A20) <= 1e-3f * fabsf(A2[n]));

  float bias = 0.f;
  if (!PRE) {
    const float* dtw = dir ? dtwr : dtwf;
    #pragma unroll
    for (int r = 0; r < DTR; r += 4) {
      const float4 v = *(const float4*)(dtw + e * DTR + r);
      dw[r] = v.x; dw[r+1] = v.y; dw[r+2] = v.z; dw[r+3] = v.w;
    }
    bias = (dir ? dtbr : dtbf)[e];
  }

  const int g = (dir * 2 + b) * DI + e;
  const size_t cb = (size_t)c * NCHAN + (size_t)g * DS;
  #pragma unroll
  for (int n = 0; n < DS; n++) h[n] = hin[cb + n];
  const size_t m0 = (size_t)b * SEQ + (size_t)c * ct;

  auto core = [&](auto sc) {
    constexpr bool S = decltype(sc)::value;
    for (int t = 0; t < ct; t++) {
      const size_t m = m0 + t;
      float d;
      union { uint4 v[4]; u16 s[32]; } BC;
      #pragma unroll
      for (int q = 0; q < 4; q++) BC.v[q] = ((const uint4*)(xdbl + m * 64 + 32))[q];
      if (PRE) {
        d = bf2f(dpre[m * DI + e]);
      } else {
        union { uint4 v[4]; u16 s[32]; } DT;
        #pragma unroll
        for (int q = 0; q < 4; q++) DT.v[q] = ((const uint4*)(xdbl + m * 64))[q];
        float a0 = 0.f, a1 = 0.f, a2 = 0.f, a3 = 0.f;
        #pragma unroll
        for (int r = 0; r < DTR; r += 4) {
          a0 += bf2f(DT.s[r+0]) * dw[r+0];
          a1 += bf2f(DT.s[r+1]) * dw[r+1];
          a2 += bf2f(DT.s[r+2]) * dw[r+2];
          a3 += bf2f(DT.s[r+3]) * dw[r+3];
        }
        d = softplus_f(((a0 + a1) + (a2 + a3)) + bias);
      }
      const float xv  = bf2f(x[m * DI + e]);
      const float dbx = d * xv;
      float dAv[DS];
      dA_calc<S>(d, A2, A20, dAv);
      float y = 0.f;
      #pragma unroll
      for (int n = 0; n < DS; n++) {
        h[n] = dAv[n] * h[n] + dbx * bf2f(BC.s[n]);
        y += h[n] * bf2f(BC.s[16 + n]);
      }
      const float yout = y + xv * dskip;
      if (MODE == 0) {
        if (dir == 0) {
          yf[m * DI + e] = f2bf(yout);
        } else {
          const size_t mo = (size_t)b * SEQ + (SEQ - 1 - (c * ct + t));
          yr[mo * DI + e] = f2bf(yout);
        }
      } else if (MODE == 1) {
        yf[m * DI + e] = f2bf(yout);
      } else {
        const size_t mo = (size_t)b * SEQ + (SEQ - 1 - (c * ct + t));
        const size_t moi = mo * DI + e;
        yr[moi] = f2bf((bf2f(yf[moi]) + yout) * bf2f(szp[moi]));
      }
    }
  };
  if (structured) core(TrueT{}); else core(FalseT{});
}

// Elementwise combine (big path): yf = (yf + yr) * sz, 8 bf16 per thread.
__global__ __launch_bounds__(256) void comb_k(
    u16* __restrict__ yfp, const u16* __restrict__ yrp, const u16* __restrict__ szp)
{
  const size_t i = ((size_t)blockIdx.x * 256 + threadIdx.x) * 8;
  union { uint4 v; u16 s[8]; } A, Bq, S, O;
  A.v  = *(const uint4*)(yfp + i);
  Bq.v = *(const uint4*)(yrp + i);
  S.v  = *(const uint4*)(szp + i);
  #pragma unroll
  for (int j = 0; j < 8; j++)
    O.s[j] = f2bf((bf2f(A.s[j]) + bf2f(Bq.s[j])) * bf2f(S.s[j]));
  *(uint4*)(yfp + i) = O.v;
}

// ---------------------------------------------------------------------------
extern "C" void kernel_launch(void* const* d_in, const int* in_sizes, int n_in,
                              void* d_out, int out_size, void* d_ws, size_t ws_size,
                              hipStream_t stream)
{
  (void)in_sizes; (void)n_in; (void)out_size;
  const float* u      = (const float*)d_in[0];
  const float* in_w   = (const float*)d_in[1];
  const float* out_w  = (const float*)d_in[2];
  const float* cw_f   = (const float*)d_in[3];
  const float* cb_f   = (const float*)d_in[4];
  const float* xw_f   = (const float*)d_in[5];
  const float* dtw_f  = (const float*)d_in[6];
  const float* dtb_f  = (const float*)d_in[7];
  const float* Alog_f = (const float*)d_in[8];
  const float* D_f    = (const float*)d_in[9];
  const float* cw_r   = (const float*)d_in[10];
  const float* cb_r   = (const float*)d_in[11];
  const float* xw_r   = (const float*)d_in[12];
  const float* dtw_r  = (const float*)d_in[13];
  const float* dtb_r  = (const float*)d_in[14];
  const float* Alog_r = (const float*)d_in[15];
  const float* D_r    = (const float*)d_in[16];

  const size_t mexe = (size_t)M_TOT * DI;          // 16.78M elements
  // big layout needs: 3*33.55 + 2*2.1 + 2.1 + 33.55 + 2*33.55 MB = 207.6 MB
  const size_t need_big =
      3 * (mexe * 2) + 2 * ((size_t)M_TOT * 64 * 2) +
      (size_t)128 * NG * 4 + (size_t)128 * NCHAN * 4 + 2 * (mexe * 2) +
      16 * 256;  // alloc padding slack
  const bool big = (ws_size >= need_big);
  const int nchunk = big ? 128 : 64;
  const int ct = SEQ / nchunk;

  char* ws = (char*)d_ws;
  size_t off = 0;
  auto alloc = [&](size_t bytes) -> void* {
    void* p = ws + off;
    off += (bytes + 255) & ~(size_t)255;
    return p;
  };
  u16*   xpre  = (u16*)alloc(mexe * 2);            // dead after conv -> yr / Yb
  u16*   xf    = (u16*)alloc(mexe * 2);            // x_f; in-place y_f
  u16*   xr    = (u16*)alloc(mexe * 2);
  u16*   xdblf = (u16*)alloc((size_t)M_TOT * 64 * 2);
  u16*   xdblr = (u16*)alloc((size_t)M_TOT * 64 * 2);
  float* sumdP = (float*)alloc((size_t)nchunk * NG * 4);
  float* bP    = (float*)alloc((size_t)nchunk * NCHAN * 4);
  u16*   df    = nullptr, *dr = nullptr;
  if (big) { df = (u16*)alloc(mexe * 2); dr = (u16*)alloc(mexe * 2); }
  u16*   szb   = (u16*)d_out;                      // silu(z) in d_out (dead before out_proj)

  dim3 blk(256);
  // 1) in_proj: xz = u @ in_w^T ; split -> xpre(bf16), sz=silu(z) in d_out
  gemm_k<128, 0, true, false><<<dim3(128, 16), blk, 0, stream>>>(
      u, nullptr, DM, in_w, nullptr, DM, xpre, nullptr, szb, nullptr, nullptr, 0);
  // 2) depthwise conv + silu, both dirs
  conv_k<<<dim3(128, 4), blk, 0, stream>>>(xpre, cw_f, cb_f, cw_r, cb_r, xf, xr);
  // 3) xproj (dual): xdbl = x @ xproj_w^T
  gemm_k<64, 1, false, true><<<dim3(128, 1, 2), blk, 0, stream>>>(
      xf, xr, DI, xw_f, xw_r, DI, xdblf, xdblr, nullptr, nullptr, nullptr, 64);

  if (big) {
    // 4) delta (dual): softplus(xdbl[:, :32] @ dtw^T + dtb) -> bf16
    gemm_k<128, 2, false, true><<<dim3(128, 8, 2), blk, 0, stream>>>(
        xdblf, xdblr, 64, dtw_f, dtw_r, DTR, df, dr, nullptr, dtb_f, dtb_r, DI);
    // 5) scan
    scanA_k<true><<<dim3(4, nchunk, 4), blk, 0, stream>>>(
        xdblf, xdblr, xf, xr, Alog_f, Alog_r, dtw_f, dtw_r, dtb_f, dtb_r,
        df, dr, sumdP, bP, ct);
    scanB_k<<<dim3(NCHAN / 256), blk, 0, stream>>>(sumdP, bP, Alog_f, Alog_r, nchunk);
    scanC_k<true, 0><<<dim3(4, nchunk, 4), blk, 0, stream>>>(
        xdblf, xdblr, xf, xr, Alog_f, Alog_r, dtw_f, dtw_r, dtb_f, dtb_r,
        df, dr, D_f, D_r, bP, xf, xpre, nullptr, ct);
    // 6) combine: yf = (yf + yr) * silu(z)
    comb_k<<<dim3((unsigned)(mexe / 8 / 256)), blk, 0, stream>>>(xf, xpre, szb);
    // 7) out_proj from xf
    gemm_k<128, 3, false, false><<<dim3(128, 4), blk, 0, stream>>>(
        xf, nullptr, DI, out_w, nullptr, DI, d_out, nullptr, nullptr, nullptr, nullptr, DM);
  } else {
    // legacy (low-ws) path: on-the-fly delta, serialized scanC
    scanA_k<false><<<dim3(4, nchunk, 4), blk, 0, stream>>>(
        xdblf, xdblr, xf, xr, Alog_f, Alog_r, dtw_f, dtw_r, dtb_f, dtb_r,
        nullptr, nullptr, sumdP, bP, ct);
    scanB_k<<<dim3(NCHAN / 256), blk, 0, stream>>>(sumdP, bP, Alog_f, Alog_r, nchunk);
    scanC_k<false, 1><<<dim3(4, nchunk, 2), blk, 0, stream>>>(
        xdblf, xdblr, xf, xr, Alog_f, Alog_r, dtw_f, dtw_r, dtb_f, dtb_r,
        nullptr, nullptr, D_f, D_r, bP, xf, nullptr, nullptr, ct);
    scanC_k<false, 2><<<dim3(4, nchunk, 2), blk, 0, stream>>>(
        xdblf, xdblr, xf, xr, Alog_f, Alog_r, dtw_f, dtw_r, dtb_f, dtb_r,
        nullptr, nullptr, D_f, D_r, bP, xf, xpre, szb, ct);
    gemm_k<128, 3, false, false><<<dim3(128, 4), blk, 0, stream>>>(
        xpre, nullptr, DI, out_w, nullptr, DI, d_out, nullptr, nullptr, nullptr, nullptr, DM);
  }
}

// Round 5
// 436.980 us; speedup vs baseline: 2.2161x; 1.1591x over previous
//
#include <hip/hip_runtime.h>
#include <hip/hip_bf16.h>
#include <math.h>

#define B_SZ 2
#define SEQ  8192
#define DM   512
#define DI   1024
#define DS   16
#define DTR  32
#define M_TOT (B_SZ*SEQ)        // 16384 positions
#define LOG2E 1.44269504088896f
#define NCHAN  (4*DI*DS)        // 65536 scan channels ((dir*2+b)*DI+e)*DS+n
#define NG     (4*DI)           // 4096 (dir,b,e) groups

typedef __attribute__((ext_vector_type(8))) short bf16x8;
typedef __attribute__((ext_vector_type(4))) float f32x4;
typedef unsigned short u16;

struct TrueT  { static constexpr bool value = true;  };
struct FalseT { static constexpr bool value = false; };

__device__ __forceinline__ float bf2f(u16 u){
  union { unsigned u; float f; } v; v.u = ((unsigned)u) << 16; return v.f;
}
__device__ __forceinline__ u16 f2bf(float f){
  union { float f; unsigned u; } v; v.f = f;
  unsigned r = v.u + 0x7FFFu + ((v.u >> 16) & 1u);
  return (u16)(r >> 16);
}
__device__ __forceinline__ float silu_f(float x){ return x / (1.f + __expf(-x)); }
__device__ __forceinline__ float softplus_f(float x){
  return (x > 15.f) ? x : __logf(1.f + __expf(x));
}

// dA[n] = exp2(A2[n]*d); structured fast path uses dA[n] = q^(n+1), q=exp2(A20*d)
template<bool S>
__device__ __forceinline__ void dA_calc(float d, const float* A2, float A20, float* dAv){
  if (S) {
    const float q = exp2f(A20 * d);
    dAv[0]  = q;
    dAv[1]  = q * q;
    dAv[2]  = dAv[1] * q;
    dAv[3]  = dAv[1] * dAv[1];
    dAv[4]  = dAv[3] * q;
    dAv[5]  = dAv[3] * dAv[1];
    dAv[6]  = dAv[3] * dAv[2];
    dAv[7]  = dAv[3] * dAv[3];
    dAv[8]  = dAv[7] * q;
    dAv[9]  = dAv[7] * dAv[1];
    dAv[10] = dAv[7] * dAv[2];
    dAv[11] = dAv[7] * dAv[3];
    dAv[12] = dAv[7] * dAv[4];
    dAv[13] = dAv[7] * dAv[5];
    dAv[14] = dAv[7] * dAv[6];
    dAv[15] = dAv[7] * dAv[7];
  } else {
    #pragma unroll
    for (int n = 0; n < DS; n++) dAv[n] = exp2f(A2[n] * d);
  }
}

// ---------------------------------------------------------------------------
// f32 -> bf16 bulk convert, 8 elems/thread (exact grid, no bounds check).
// ---------------------------------------------------------------------------
__global__ __launch_bounds__(256) void cvt_k(
    const float* __restrict__ s, u16* __restrict__ d)
{
  const size_t i = (size_t)blockIdx.x * 256 + threadIdx.x;
  const float4 a = ((const float4*)s)[i * 2];
  const float4 b = ((const float4*)s)[i * 2 + 1];
  union { uint4 v; u16 h[8]; } o;
  o.h[0] = f2bf(a.x); o.h[1] = f2bf(a.y); o.h[2] = f2bf(a.z); o.h[3] = f2bf(a.w);
  o.h[4] = f2bf(b.x); o.h[5] = f2bf(b.y); o.h[6] = f2bf(b.z); o.h[7] = f2bf(b.w);
  ((uint4*)d)[i] = o.v;
}

// Packed weight convert: 6 tensors -> one bf16 arena. Unit = 8 elems.
// Layout (units): in_w 131072 | xw_f 8192 | xw_r 8192 | dtw_f 4096 | dtw_r 4096 | out_w 65536
#define WU_INW  131072
#define WU_XW   8192
#define WU_DTW  4096
#define WU_OUTW 65536
#define WU_TOT  (WU_INW + 2*WU_XW + 2*WU_DTW + WU_OUTW)   // 221184
__global__ __launch_bounds__(256) void cvtw_k(
    const float* __restrict__ inw, const float* __restrict__ xwf,
    const float* __restrict__ xwr, const float* __restrict__ dtwf,
    const float* __restrict__ dtwr, const float* __restrict__ outw,
    u16* __restrict__ dst)
{
  int i = blockIdx.x * 256 + threadIdx.x;
  const float* s;
  int base = 0;
  if (i < WU_INW) { s = inw; }
  else if ((i -= WU_INW) < WU_XW) { s = xwf; base = WU_INW; }
  else if ((i -= WU_XW) < WU_XW)  { s = xwr; base = WU_INW + WU_XW; }
  else if ((i -= WU_XW) < WU_DTW) { s = dtwf; base = WU_INW + 2*WU_XW; }
  else if ((i -= WU_DTW) < WU_DTW){ s = dtwr; base = WU_INW + 2*WU_XW + WU_DTW; }
  else { i -= WU_DTW; s = outw; base = WU_INW + 2*WU_XW + 2*WU_DTW; }
  const float4 a = ((const float4*)s)[i * 2];
  const float4 b = ((const float4*)s)[i * 2 + 1];
  union { uint4 v; u16 h[8]; } o;
  o.h[0] = f2bf(a.x); o.h[1] = f2bf(a.y); o.h[2] = f2bf(a.z); o.h[3] = f2bf(a.w);
  o.h[4] = f2bf(b.x); o.h[5] = f2bf(b.y); o.h[6] = f2bf(b.z); o.h[7] = f2bf(b.w);
  ((uint4*)(dst))[base + i] = o.v;
}

// ---------------------------------------------------------------------------
// MFMA bf16 GEMM, m97-style staging: C[m,n] = sum_k A[m,k]*W[n,k]
//   A, W bf16 row-major. global_load_lds width-16 into linear LDS [rows][32].
//   BM=128, BK=32, BN in {64,128}. 256 threads = 4 waves, 64x64 per wave.
// EPI: 0 = split xz -> out0(bf16), out1=silu (bf16)   (in_proj, N=2048)
//      1 = store bf16 (ldo)                            (xproj)
//      2 = softplus(acc + bias[n]) -> bf16 (ldo)       (delta proj)
//      3 = store f32 (ldo)                             (out_proj)
// DUAL: blockIdx.z selects pointer set (merged fwd/rev launches)
// ---------------------------------------------------------------------------
template<int BN, int EPI, bool DUAL>
__global__ __launch_bounds__(256) void gemm_k(
    const u16* __restrict__ Ap,  const u16* __restrict__ Ap2, int lda,
    const u16* __restrict__ Bw,  const u16* __restrict__ Bw2, int K,
    void* __restrict__ out0, void* __restrict__ out02,
    void* __restrict__ out1,
    const float* __restrict__ bias, const float* __restrict__ bias2, int ldo)
{
  constexpr int BM = 128, BK = 32;
  __shared__ __align__(16) u16 As[BM * BK];
  __shared__ __align__(16) u16 Bs[BN * BK];
  const int tid  = threadIdx.x;
  const int lane = tid & 63, wid = tid >> 6;
  const int mt = blockIdx.x, nt = blockIdx.y;
  const int z  = DUAL ? blockIdx.z : 0;
  const u16* A = z ? Ap2 : Ap;
  const u16* W = z ? Bw2 : Bw;
  void* o0 = z ? out02 : out0;
  const float* bi = z ? bias2 : bias;

  constexpr int FM = (BN == 128) ? 4 : 2;
  const int wm = (BN == 128) ? ((wid >> 1) * 64) : (wid * 32);
  const int wn = (BN == 128) ? ((wid & 1) * 64) : 0;

  f32x4 acc[FM][4];
  #pragma unroll
  for (int i = 0; i < FM; i++)
    #pragma unroll
    for (int j = 0; j < 4; j++)
      acc[i][j] = (f32x4){0.f, 0.f, 0.f, 0.f};

  // staging decomposition: each wave-issue covers 16 rows x 32 cols (1 KiB).
  const int sr = lane >> 2;          // row within 16-row chunk
  const int sc = (lane & 3) * 8;     // col (shorts): 0,8,16,24

  for (int k0 = 0; k0 < K; k0 += BK) {
    #pragma unroll
    for (int j = 0; j < 2; j++) {    // A: 8 chunks, 2 per wave
      const int chunk = wid * 2 + j;
      const u16* src = A + (size_t)(mt * BM + chunk * 16 + sr) * lda + (k0 + sc);
      __builtin_amdgcn_global_load_lds(
          (const __attribute__((address_space(1))) void*)src,
          (__attribute__((address_space(3))) void*)(As + chunk * 512), 16, 0, 0);
    }
    #pragma unroll
    for (int j = 0; j < BN / 64; j++) {  // B: BN/16 chunks, BN/64 per wave
      const int chunk = wid * (BN / 64) + j;
      const u16* src = W + (size_t)(nt * BN + chunk * 16 + sr) * K + (k0 + sc);
      __builtin_amdgcn_global_load_lds(
          (const __attribute__((address_space(1))) void*)src,
          (__attribute__((address_space(3))) void*)(Bs + chunk * 512), 16, 0, 0);
    }
    __syncthreads();   // compiler emits vmcnt(0) drain before s_barrier

    const int row = lane & 15, kq = (lane >> 4) * 8;
    bf16x8 af[FM], bfr[4];
    #pragma unroll
    for (int i = 0; i < FM; i++) af[i] = *(const bf16x8*)&As[(wm + i * 16 + row) * BK + kq];
    #pragma unroll
    for (int j = 0; j < 4; j++)  bfr[j] = *(const bf16x8*)&Bs[(wn + j * 16 + row) * BK + kq];
    #pragma unroll
    for (int i = 0; i < FM; i++)
      #pragma unroll
      for (int j = 0; j < 4; j++)
        acc[i][j] = __builtin_amdgcn_mfma_f32_16x16x32_bf16(af[i], bfr[j], acc[i][j], 0, 0, 0);
    __syncthreads();
  }

  const int rb4 = (lane >> 4) * 4, col = lane & 15;
  #pragma unroll
  for (int i = 0; i < FM; i++) {
    #pragma unroll
    for (int j = 0; j < 4; j++) {
      #pragma unroll
      for (int r = 0; r < 4; r++) {
        const int m = mt * BM + wm + i * 16 + rb4 + r;
        const int n = nt * BN + wn + j * 16 + col;
        const float v = acc[i][j][r];
        if (EPI == 0) {
          if (n < DI) ((u16*)o0)[(size_t)m * DI + n] = f2bf(v);
          else        ((u16*)out1)[(size_t)m * DI + (n - DI)] = f2bf(silu_f(v));
        } else if (EPI == 1) {
          ((u16*)o0)[(size_t)m * ldo + n] = f2bf(v);
        } else if (EPI == 2) {
          ((u16*)o0)[(size_t)m * ldo + n] = f2bf(softplus_f(v + bi[n]));
        } else {
          ((float*)o0)[(size_t)m * ldo + n] = v;
        }
      }
    }
  }
}

// ---------------------------------------------------------------------------
// Depthwise causal conv(4) + bias + silu, both directions.
// grid: (128 l-tiles of 64, b + 2*dir)
// ---------------------------------------------------------------------------
__global__ __launch_bounds__(256) void conv_k(
    const u16* __restrict__ xpre,
    const float* __restrict__ wf, const float* __restrict__ bf_,
    const float* __restrict__ wr, const float* __restrict__ br_,
    u16* __restrict__ xf, u16* __restrict__ xr)
{
  const int lt  = blockIdx.x;
  const int b   = blockIdx.y & 1;
  const int dir = blockIdx.y >> 1;
  const int tid = threadIdx.x;
  const float* w  = dir ? wr : wf;
  const float* bb = dir ? br_ : bf_;
  u16* xo = dir ? xr : xf;
  const int l0 = lt * 64;
  for (int j = 0; j < 4; j++) {
    const int e = j * 256 + tid;
    const float w0 = w[e*4+0], w1 = w[e*4+1], w2 = w[e*4+2], w3 = w[e*4+3], bv = bb[e];
    const size_t base = (size_t)b * SEQ * DI + e;
    auto load = [&](int q) -> float {
      if (q < 0) return 0.f;
      const int li = dir ? (SEQ - 1 - q) : q;
      return bf2f(xpre[base + (size_t)li * DI]);
    };
    float h0 = load(l0 - 3), h1 = load(l0 - 2), h2 = load(l0 - 1);
    for (int l = l0; l < l0 + 64; l++) {
      const float h3 = load(l);
      const float v = bv + w0*h0 + w1*h1 + w2*h2 + w3*h3;
      xo[base + (size_t)l * DI] = f2bf(silu_f(v));
      h0 = h1; h1 = h2; h2 = h3;
    }
  }
}

// ---------------------------------------------------------------------------
// Scan pass A (merged dirs): per (dir,b,chunk,e) chunk-local scan from h=0.
// PRE: delta precomputed (bf16). Otherwise on-the-fly (4-acc dot + softplus).
// grid: (4 e-blocks, nchunk, 4=dir*2+b)
// ---------------------------------------------------------------------------
template<bool PRE>
__global__ __launch_bounds__(256) void scanA_k(
    const u16* __restrict__ xdblf_, const u16* __restrict__ xdblr_,
    const u16* __restrict__ xf_,    const u16* __restrict__ xr_,
    const float* __restrict__ Alf,  const float* __restrict__ Alr,
    const float* __restrict__ dtwf, const float* __restrict__ dtwr,
    const float* __restrict__ dtbf, const float* __restrict__ dtbr,
    const u16* __restrict__ df_,    const u16* __restrict__ dr_,
    float* __restrict__ sumdP, float* __restrict__ bP, int ct)
{
  const int e = blockIdx.x * 256 + threadIdx.x;
  const int c = blockIdx.y;
  const int dir = blockIdx.z >> 1, b = blockIdx.z & 1;
  const u16* xdbl = dir ? xdblr_ : xdblf_;
  const u16* x    = dir ? xr_ : xf_;
  const float* Al = dir ? Alr : Alf;
  const u16* dpre = dir ? dr_ : df_;

  float A2[DS], h[DS], dw[DTR];
  #pragma unroll
  for (int n = 0; n < DS; n++) { A2[n] = -__expf(Al[e * DS + n]) * LOG2E; h[n] = 0.f; }
  const float A20 = A2[0];
  bool structured = true;
  #pragma unroll
  for (int n = 1; n < DS; n++)
    structured = structured && (fabsf(A2[n] - (float)(n + 1) * A20) <= 1e-3f * fabsf(A2[n]));

  float bias = 0.f;
  if (!PRE) {
    const float* dtw = dir ? dtwr : dtwf;
    #pragma unroll
    for (int r = 0; r < DTR; r += 4) {
      const float4 v = *(const float4*)(dtw + e * DTR + r);
      dw[r] = v.x; dw[r+1] = v.y; dw[r+2] = v.z; dw[r+3] = v.w;
    }
    bias = (dir ? dtbr : dtbf)[e];
  }

  float sumd = 0.f;
  const size_t m0 = (size_t)b * SEQ + (size_t)c * ct;

  auto core = [&](auto sc) {
    constexpr bool S = decltype(sc)::value;
    for (int t = 0; t < ct; t++) {
      const size_t m = m0 + t;
      float d;
      if (PRE) {
        d = bf2f(dpre[m * DI + e]);
      } else {
        union { uint4 v[4]; u16 s[32]; } DT;
        #pragma unroll
        for (int q = 0; q < 4; q++) DT.v[q] = ((const uint4*)(xdbl + m * 64))[q];
        float a0 = 0.f, a1 = 0.f, a2 = 0.f, a3 = 0.f;
        #pragma unroll
        for (int r = 0; r < DTR; r += 4) {
          a0 += bf2f(DT.s[r+0]) * dw[r+0];
          a1 += bf2f(DT.s[r+1]) * dw[r+1];
          a2 += bf2f(DT.s[r+2]) * dw[r+2];
          a3 += bf2f(DT.s[r+3]) * dw[r+3];
        }
        d = softplus_f(((a0 + a1) + (a2 + a3)) + bias);
      }
      const float xv  = bf2f(x[m * DI + e]);
      const float dbx = d * xv;
      sumd += d;
      union { uint4 v[2]; u16 s[16]; } Bv;
      Bv.v[0] = ((const uint4*)(xdbl + m * 64 + 32))[0];
      Bv.v[1] = ((const uint4*)(xdbl + m * 64 + 32))[1];
      float dAv[DS];
      dA_calc<S>(d, A2, A20, dAv);
      #pragma unroll
      for (int n = 0; n < DS; n++)
        h[n] = dAv[n] * h[n] + dbx * bf2f(Bv.s[n]);
    }
  };
  if (structured) core(TrueT{}); else core(FalseT{});

  const int g = (dir * 2 + b) * DI + e;
  const size_t cb = (size_t)c * NCHAN + (size_t)g * DS;
  #pragma unroll
  for (int n = 0; n < DS; n++) bP[cb + n] = h[n];
  sumdP[(size_t)c * NG + g] = sumd;
}

// Scan pass B: cross-chunk scan, in place (bP becomes h_in per chunk).
__global__ __launch_bounds__(256) void scanB_k(
    const float* __restrict__ sumdP, float* __restrict__ bP,
    const float* __restrict__ Alog_f, const float* __restrict__ Alog_r, int nchunk)
{
  const int ch = blockIdx.x * 256 + threadIdx.x;   // 0..65535
  const int g = ch >> 4, n = ch & 15;
  const int dir = g >> 11, e = g & (DI - 1);
  const float* Al = dir ? Alog_r : Alog_f;
  const float A2 = -__expf(Al[e * DS + n]) * LOG2E;
  float h = 0.f;
  for (int c = 0; c < nchunk; c++) {
    const float a = exp2f(A2 * sumdP[(size_t)c * NG + g]);
    const size_t i = (size_t)c * NCHAN + ch;
    const float bb = bP[i];
    bP[i] = h;              // h_in for chunk c
    h = a * h + bb;
  }
}

// ---------------------------------------------------------------------------
// Scan pass C: replay chunk from h_in, emit y (+ x*D).
// MODE 0: merged dirs (z=dir*2+b). dir0 -> yf[m] (in place over x_f);
//         dir1 -> yr[mo] (mo = flipped). No sz/Yf read.
// MODE 1: legacy dir0 only (z=b): yf[m] = y + x*D
// MODE 2: legacy dir1 combine (z=b): yr[mo] = (yf[mo] + y + x*D) * sz[mo]
// ---------------------------------------------------------------------------
template<bool PRE, int MODE>
__global__ __launch_bounds__(256) void scanC_k(
    const u16* __restrict__ xdblf_, const u16* __restrict__ xdblr_,
    const u16* __restrict__ xf_,    const u16* __restrict__ xr_,
    const float* __restrict__ Alf,  const float* __restrict__ Alr,
    const float* __restrict__ dtwf, const float* __restrict__ dtwr,
    const float* __restrict__ dtbf, const float* __restrict__ dtbr,
    const u16* __restrict__ df_,    const u16* __restrict__ dr_,
    const float* __restrict__ Dskf, const float* __restrict__ Dskr,
    const float* __restrict__ hin,
    u16* __restrict__ yf, u16* __restrict__ yr,
    const u16* __restrict__ szp, int ct)
{
  const int e = blockIdx.x * 256 + threadIdx.x;
  const int c = blockIdx.y;
  int dir, b;
  if (MODE == 0) { dir = blockIdx.z >> 1; b = blockIdx.z & 1; }
  else           { dir = (MODE == 2);     b = blockIdx.z; }
  const u16* xdbl = dir ? xdblr_ : xdblf_;
  const u16* x    = dir ? xr_ : xf_;
  const float* Al = dir ? Alr : Alf;
  const u16* dpre = dir ? dr_ : df_;
  const float dskip = (dir ? Dskr : Dskf)[e];

  float A2[DS], h[DS], dw[DTR];
  #pragma unroll
  for (int n = 0; n < DS; n++) A2[n] = -__expf(Al[e * DS + n]) * LOG2E;
  const float A20 = A2[0];
  bool structured = true;
  #pragma unroll
  for (int n = 1; n < DS; n++)
    structured = structured && (fabsf(A2[n] - (float)(n + 1) * A20) <= 1e-3f * fabsf(A2[n]));

  float bias = 0.f;
  if (!PRE) {
    const float* dtw = dir ? dtwr : dtwf;
    #pragma unroll
    for (int r = 0; r < DTR; r += 4) {
      const float4 v = *(const float4*)(dtw + e * DTR + r);
      dw[r] = v.x; dw[r+1] = v.y; dw[r+2] = v.z; dw[r+3] = v.w;
    }
    bias = (dir ? dtbr : dtbf)[e];
  }

  const int g = (dir * 2 + b) * DI + e;
  const size_t cb = (size_t)c * NCHAN + (size_t)g * DS;
  #pragma unroll
  for (int n = 0; n < DS; n++) h[n] = hin[cb + n];
  const size_t m0 = (size_t)b * SEQ + (size_t)c * ct;

  auto core = [&](auto sc) {
    constexpr bool S = decltype(sc)::value;
    for (int t = 0; t < ct; t++) {
      const size_t m = m0 + t;
      float d;
      union { uint4 v[4]; u16 s[32]; } BC;
      #pragma unroll
      for (int q = 0; q < 4; q++) BC.v[q] = ((const uint4*)(xdbl + m * 64 + 32))[q];
      if (PRE) {
        d = bf2f(dpre[m * DI + e]);
      } else {
        union { uint4 v[4]; u16 s[32]; } DT;
        #pragma unroll
        for (int q = 0; q < 4; q++) DT.v[q] = ((const uint4*)(xdbl + m * 64))[q];
        float a0 = 0.f, a1 = 0.f, a2 = 0.f, a3 = 0.f;
        #pragma unroll
        for (int r = 0; r < DTR; r += 4) {
          a0 += bf2f(DT.s[r+0]) * dw[r+0];
          a1 += bf2f(DT.s[r+1]) * dw[r+1];
          a2 += bf2f(DT.s[r+2]) * dw[r+2];
          a3 += bf2f(DT.s[r+3]) * dw[r+3];
        }
        d = softplus_f(((a0 + a1) + (a2 + a3)) + bias);
      }
      const float xv  = bf2f(x[m * DI + e]);
      const float dbx = d * xv;
      float dAv[DS];
      dA_calc<S>(d, A2, A20, dAv);
      float y = 0.f;
      #pragma unroll
      for (int n = 0; n < DS; n++) {
        h[n] = dAv[n] * h[n] + dbx * bf2f(BC.s[n]);
        y += h[n] * bf2f(BC.s[16 + n]);
      }
      const float yout = y + xv * dskip;
      if (MODE == 0) {
        if (dir == 0) {
          yf[m * DI + e] = f2bf(yout);
        } else {
          const size_t mo = (size_t)b * SEQ + (SEQ - 1 - (c * ct + t));
          yr[mo * DI + e] = f2bf(yout);
        }
      } else if (MODE == 1) {
        yf[m * DI + e] = f2bf(yout);
      } else {
        const size_t mo = (size_t)b * SEQ + (SEQ - 1 - (c * ct + t));
        const size_t moi = mo * DI + e;
        yr[moi] = f2bf((bf2f(yf[moi]) + yout) * bf2f(szp[moi]));
      }
    }
  };
  if (structured) core(TrueT{}); else core(FalseT{});
}

// Elementwise combine (big path): yf = (yf + yr) * sz, 8 bf16 per thread.
__global__ __launch_bounds__(256) void comb_k(
    u16* __restrict__ yfp, const u16* __restrict__ yrp, const u16* __restrict__ szp)
{
  const size_t i = ((size_t)blockIdx.x * 256 + threadIdx.x) * 8;
  union { uint4 v; u16 s[8]; } A, Bq, S, O;
  A.v  = *(const uint4*)(yfp + i);
  Bq.v = *(const uint4*)(yrp + i);
  S.v  = *(const uint4*)(szp + i);
  #pragma unroll
  for (int j = 0; j < 8; j++)
    O.s[j] = f2bf((bf2f(A.s[j]) + bf2f(Bq.s[j])) * bf2f(S.s[j]));
  *(uint4*)(yfp + i) = O.v;
}

// ---------------------------------------------------------------------------
extern "C" void kernel_launch(void* const* d_in, const int* in_sizes, int n_in,
                              void* d_out, int out_size, void* d_ws, size_t ws_size,
                              hipStream_t stream)
{
  (void)in_sizes; (void)n_in; (void)out_size;
  const float* u      = (const float*)d_in[0];
  const float* in_w   = (const float*)d_in[1];
  const float* out_w  = (const float*)d_in[2];
  const float* cw_f   = (const float*)d_in[3];
  const float* cb_f   = (const float*)d_in[4];
  const float* xw_f   = (const float*)d_in[5];
  const float* dtw_f  = (const float*)d_in[6];
  const float* dtb_f  = (const float*)d_in[7];
  const float* Alog_f = (const float*)d_in[8];
  const float* D_f    = (const float*)d_in[9];
  const float* cw_r   = (const float*)d_in[10];
  const float* cb_r   = (const float*)d_in[11];
  const float* xw_r   = (const float*)d_in[12];
  const float* dtw_r  = (const float*)d_in[13];
  const float* dtb_r  = (const float*)d_in[14];
  const float* Alog_r = (const float*)d_in[15];
  const float* D_r    = (const float*)d_in[16];

  const size_t mexe = (size_t)M_TOT * DI;          // 16.78M elements
  // big layout: ubf(=df) + xpre + xf + xr + xdbl*2 + wbf + sumdP128 + bP128 + dr ~= 215 MB
  const size_t need_big =
      5 * (mexe * 2) + 2 * ((size_t)M_TOT * 64 * 2) + (size_t)WU_TOT * 16 +
      (size_t)128 * NG * 4 + (size_t)128 * NCHAN * 4 + 32 * 256;
  const bool big = (ws_size >= need_big);
  const int nchunk = big ? 128 : 64;
  const int ct = SEQ / nchunk;

  char* ws = (char*)d_ws;
  size_t off = 0;
  auto alloc = [&](size_t bytes) -> void* {
    void* p = ws + off;
    off += (bytes + 255) & ~(size_t)255;
    return p;
  };
  u16*   ubf   = (u16*)alloc(mexe * 2);            // bf16 u (8.39M used); dead after in_proj -> df
  u16*   xpre  = (u16*)alloc(mexe * 2);            // dead after conv -> yr
  u16*   xf    = (u16*)alloc(mexe * 2);            // x_f; in-place y_f
  u16*   xr    = (u16*)alloc(mexe * 2);
  u16*   xdblf = (u16*)alloc((size_t)M_TOT * 64 * 2);
  u16*   xdblr = (u16*)alloc((size_t)M_TOT * 64 * 2);
  u16*   wbf   = (u16*)alloc((size_t)WU_TOT * 16); // bf16 weight arena
  float* sumdP = (float*)alloc((size_t)nchunk * NG * 4);
  float* bP    = (float*)alloc((size_t)nchunk * NCHAN * 4);
  u16*   dr    = big ? (u16*)alloc(mexe * 2) : nullptr;
  u16*   df    = ubf;                              // alias (u dead after in_proj)
  u16*   szb   = (u16*)d_out;                      // silu(z) in d_out (dead before out_proj)

  // weight arena sub-pointers (units of 8 elems = 16 B)
  u16* winb  = wbf;
  u16* xwbf  = wbf + (size_t)WU_INW * 8;
  u16* xwbr  = xwbf + (size_t)WU_XW * 8;
  u16* dtwbf = xwbr + (size_t)WU_XW * 8;
  u16* dtwbr = dtwbf + (size_t)WU_DTW * 8;
  u16* outwb = dtwbr + (size_t)WU_DTW * 8;

  dim3 blk(256);
  // 0) convert u + weights to bf16.  u has M_TOT*DM = 8.39M elems -> 4096 blocks.
  cvt_k<<<dim3((unsigned)((size_t)M_TOT * DM / 8 / 256)), blk, 0, stream>>>(u, ubf);
  cvtw_k<<<dim3(WU_TOT / 256), blk, 0, stream>>>(in_w, xw_f, xw_r, dtw_f, dtw_r, out_w, wbf);
  // 1) in_proj: xz = u @ in_w^T ; split -> xpre(bf16), sz=silu(z) in d_out
  gemm_k<128, 0, false><<<dim3(128, 16), blk, 0, stream>>>(
      ubf, nullptr, DM, winb, nullptr, DM, xpre, nullptr, szb, nullptr, nullptr, 0);
  // 2) depthwise conv + silu, both dirs
  conv_k<<<dim3(128, 4), blk, 0, stream>>>(xpre, cw_f, cb_f, cw_r, cb_r, xf, xr);
  // 3) xproj (dual): xdbl = x @ xproj_w^T
  gemm_k<64, 1, true><<<dim3(128, 1, 2), blk, 0, stream>>>(
      xf, xr, DI, xwbf, xwbr, DI, xdblf, xdblr, nullptr, nullptr, nullptr, 64);

  if (big) {
    // 4) delta (dual): softplus(xdbl[:, :32] @ dtw^T + dtb) -> bf16 (df aliases ubf)
    gemm_k<128, 2, true><<<dim3(128, 8, 2), blk, 0, stream>>>(
        xdblf, xdblr, 64, dtwbf, dtwbr, DTR, df, dr, nullptr, dtb_f, dtb_r, DI);
    // 5) scan
    scanA_k<true><<<dim3(4, nchunk, 4), blk, 0, stream>>>(
        xdblf, xdblr, xf, xr, Alog_f, Alog_r, dtw_f, dtw_r, dtb_f, dtb_r,
        df, dr, sumdP, bP, ct);
    scanB_k<<<dim3(NCHAN / 256), blk, 0, stream>>>(sumdP, bP, Alog_f, Alog_r, nchunk);
    scanC_k<true, 0><<<dim3(4, nchunk, 4), blk, 0, stream>>>(
        xdblf, xdblr, xf, xr, Alog_f, Alog_r, dtw_f, dtw_r, dtb_f, dtb_r,
        df, dr, D_f, D_r, bP, xf, xpre, nullptr, ct);
    // 6) combine: yf = (yf + yr) * silu(z)
    comb_k<<<dim3((unsigned)(mexe / 8 / 256)), blk, 0, stream>>>(xf, xpre, szb);
    // 7) out_proj from xf
    gemm_k<128, 3, false><<<dim3(128, 4), blk, 0, stream>>>(
        xf, nullptr, DI, outwb, nullptr, DI, d_out, nullptr, nullptr, nullptr, nullptr, DM);
  } else {
    // legacy (low-ws) path: on-the-fly delta, serialized scanC
    scanA_k<false><<<dim3(4, nchunk, 4), blk, 0, stream>>>(
        xdblf, xdblr, xf, xr, Alog_f, Alog_r, dtw_f, dtw_r, dtb_f, dtb_r,
        nullptr, nullptr, sumdP, bP, ct);
    scanB_k<<<dim3(NCHAN / 256), blk, 0, stream>>>(sumdP, bP, Alog_f, Alog_r, nchunk);
    scanC_k<false, 1><<<dim3(4, nchunk, 2), blk, 0, stream>>>(
        xdblf, xdblr, xf, xr, Alog_f, Alog_r, dtw_f, dtw_r, dtb_f, dtb_r,
        nullptr, nullptr, D_f, D_r, bP, xf, nullptr, nullptr, ct);
    scanC_k<false, 2><<<dim3(4, nchunk, 2), blk, 0, stream>>>(
        xdblf, xdblr, xf, xr, Alog_f, Alog_r, dtw_f, dtw_r, dtb_f, dtb_r,
        nullptr, nullptr, D_f, D_r, bP, xf, xpre, szb, ct);
    gemm_k<128, 3, false><<<dim3(128, 4), blk, 0, stream>>>(
        xpre, nullptr, DI, outwb, nullptr, DI, d_out, nullptr, nullptr, nullptr, nullptr, DM);
  }
}

// Round 6
// 374.525 us; speedup vs baseline: 2.5857x; 1.1668x over previous
//
#include <hip/hip_runtime.h>
#include <hip/hip_bf16.h>
#include <math.h>

#define B_SZ 2
#define SEQ  8192
#define DM   512
#define DI   1024
#define DS   16
#define DTR  32
#define M_TOT (B_SZ*SEQ)        // 16384 positions
#define LOG2E 1.44269504088896f
#define NCHAN  (4*DI*DS)        // 65536 scan channels ((dir*2+b)*DI+e)*DS+n
#define NG     (4*DI)           // 4096 (dir,b,e) groups
#define CLT    8                // conv timesteps per thread

typedef __attribute__((ext_vector_type(8))) short bf16x8;
typedef __attribute__((ext_vector_type(4))) float f32x4;
typedef unsigned short u16;

struct TrueT  { static constexpr bool value = true;  };
struct FalseT { static constexpr bool value = false; };

__device__ __forceinline__ float bf2f(u16 u){
  union { unsigned u; float f; } v; v.u = ((unsigned)u) << 16; return v.f;
}
__device__ __forceinline__ u16 f2bf(float f){
  union { float f; unsigned u; } v; v.f = f;
  unsigned r = v.u + 0x7FFFu + ((v.u >> 16) & 1u);
  return (u16)(r >> 16);
}
__device__ __forceinline__ float silu_f(float x){ return x / (1.f + __expf(-x)); }
__device__ __forceinline__ float softplus_f(float x){
  return (x > 15.f) ? x : __logf(1.f + __expf(x));
}

// dA[n] = exp2(A2[n]*d); structured fast path uses dA[n] = q^(n+1), q=exp2(A20*d)
template<bool S>
__device__ __forceinline__ void dA_calc(float d, const float* A2, float A20, float* dAv){
  if (S) {
    const float q = exp2f(A20 * d);
    dAv[0]  = q;
    dAv[1]  = q * q;
    dAv[2]  = dAv[1] * q;
    dAv[3]  = dAv[1] * dAv[1];
    dAv[4]  = dAv[3] * q;
    dAv[5]  = dAv[3] * dAv[1];
    dAv[6]  = dAv[3] * dAv[2];
    dAv[7]  = dAv[3] * dAv[3];
    dAv[8]  = dAv[7] * q;
    dAv[9]  = dAv[7] * dAv[1];
    dAv[10] = dAv[7] * dAv[2];
    dAv[11] = dAv[7] * dAv[3];
    dAv[12] = dAv[7] * dAv[4];
    dAv[13] = dAv[7] * dAv[5];
    dAv[14] = dAv[7] * dAv[6];
    dAv[15] = dAv[7] * dAv[7];
  } else {
    #pragma unroll
    for (int n = 0; n < DS; n++) dAv[n] = exp2f(A2[n] * d);
  }
}

// ---------------------------------------------------------------------------
// f32 -> bf16 bulk convert, 8 elems/thread (exact grid, no bounds check).
// ---------------------------------------------------------------------------
__global__ __launch_bounds__(256) void cvt_k(
    const float* __restrict__ s, u16* __restrict__ d)
{
  const size_t i = (size_t)blockIdx.x * 256 + threadIdx.x;
  const float4 a = ((const float4*)s)[i * 2];
  const float4 b = ((const float4*)s)[i * 2 + 1];
  union { uint4 v; u16 h[8]; } o;
  o.h[0] = f2bf(a.x); o.h[1] = f2bf(a.y); o.h[2] = f2bf(a.z); o.h[3] = f2bf(a.w);
  o.h[4] = f2bf(b.x); o.h[5] = f2bf(b.y); o.h[6] = f2bf(b.z); o.h[7] = f2bf(b.w);
  ((uint4*)d)[i] = o.v;
}

// Packed weight convert: 6 tensors -> one bf16 arena. Unit = 8 elems.
// Layout (units): in_w 131072 | xw_f 8192 | xw_r 8192 | dtw_f 4096 | dtw_r 4096 | out_w 65536
#define WU_INW  131072
#define WU_XW   8192
#define WU_DTW  4096
#define WU_OUTW 65536
#define WU_TOT  (WU_INW + 2*WU_XW + 2*WU_DTW + WU_OUTW)   // 221184
__global__ __launch_bounds__(256) void cvtw_k(
    const float* __restrict__ inw, const float* __restrict__ xwf,
    const float* __restrict__ xwr, const float* __restrict__ dtwf,
    const float* __restrict__ dtwr, const float* __restrict__ outw,
    u16* __restrict__ dst)
{
  int i = blockIdx.x * 256 + threadIdx.x;
  const float* s;
  int base = 0;
  if (i < WU_INW) { s = inw; }
  else if ((i -= WU_INW) < WU_XW) { s = xwf; base = WU_INW; }
  else if ((i -= WU_XW) < WU_XW)  { s = xwr; base = WU_INW + WU_XW; }
  else if ((i -= WU_XW) < WU_DTW) { s = dtwf; base = WU_INW + 2*WU_XW; }
  else if ((i -= WU_DTW) < WU_DTW){ s = dtwr; base = WU_INW + 2*WU_XW + WU_DTW; }
  else { i -= WU_DTW; s = outw; base = WU_INW + 2*WU_XW + 2*WU_DTW; }
  const float4 a = ((const float4*)s)[i * 2];
  const float4 b = ((const float4*)s)[i * 2 + 1];
  union { uint4 v; u16 h[8]; } o;
  o.h[0] = f2bf(a.x); o.h[1] = f2bf(a.y); o.h[2] = f2bf(a.z); o.h[3] = f2bf(a.w);
  o.h[4] = f2bf(b.x); o.h[5] = f2bf(b.y); o.h[6] = f2bf(b.z); o.h[7] = f2bf(b.w);
  ((uint4*)(dst))[base + i] = o.v;
}

// ---------------------------------------------------------------------------
// MFMA bf16 GEMM, m97-style staging: C[m,n] = sum_k A[m,k]*W[n,k]
//   A, W bf16 row-major. global_load_lds width-16 into linear LDS [rows][32].
//   BM=128, BK=32, BN in {64,128}. 256 threads = 4 waves, 64x64 per wave.
// EPI: 0 = split xz -> out0(bf16), out1=silu (bf16)   (in_proj, N=2048)
//      1 = store bf16 (ldo)                            (xproj)
//      2 = softplus(acc + bias[n]) -> bf16 (ldo)       (delta proj)
//      3 = store f32 (ldo)                             (out_proj)
// DUAL: blockIdx.z selects pointer set (merged fwd/rev launches)
// ---------------------------------------------------------------------------
template<int BN, int EPI, bool DUAL>
__global__ __launch_bounds__(256) void gemm_k(
    const u16* __restrict__ Ap,  const u16* __restrict__ Ap2, int lda,
    const u16* __restrict__ Bw,  const u16* __restrict__ Bw2, int K,
    void* __restrict__ out0, void* __restrict__ out02,
    void* __restrict__ out1,
    const float* __restrict__ bias, const float* __restrict__ bias2, int ldo)
{
  constexpr int BM = 128, BK = 32;
  __shared__ __align__(16) u16 As[BM * BK];
  __shared__ __align__(16) u16 Bs[BN * BK];
  const int tid  = threadIdx.x;
  const int lane = tid & 63, wid = tid >> 6;
  const int mt = blockIdx.x, nt = blockIdx.y;
  const int z  = DUAL ? blockIdx.z : 0;
  const u16* A = z ? Ap2 : Ap;
  const u16* W = z ? Bw2 : Bw;
  void* o0 = z ? out02 : out0;
  const float* bi = z ? bias2 : bias;

  constexpr int FM = (BN == 128) ? 4 : 2;
  const int wm = (BN == 128) ? ((wid >> 1) * 64) : (wid * 32);
  const int wn = (BN == 128) ? ((wid & 1) * 64) : 0;

  f32x4 acc[FM][4];
  #pragma unroll
  for (int i = 0; i < FM; i++)
    #pragma unroll
    for (int j = 0; j < 4; j++)
      acc[i][j] = (f32x4){0.f, 0.f, 0.f, 0.f};

  // staging decomposition: each wave-issue covers 16 rows x 32 cols (1 KiB).
  const int sr = lane >> 2;          // row within 16-row chunk
  const int sc = (lane & 3) * 8;     // col (shorts): 0,8,16,24

  for (int k0 = 0; k0 < K; k0 += BK) {
    #pragma unroll
    for (int j = 0; j < 2; j++) {    // A: 8 chunks, 2 per wave
      const int chunk = wid * 2 + j;
      const u16* src = A + (size_t)(mt * BM + chunk * 16 + sr) * lda + (k0 + sc);
      __builtin_amdgcn_global_load_lds(
          (const __attribute__((address_space(1))) void*)src,
          (__attribute__((address_space(3))) void*)(As + chunk * 512), 16, 0, 0);
    }
    #pragma unroll
    for (int j = 0; j < BN / 64; j++) {  // B: BN/16 chunks, BN/64 per wave
      const int chunk = wid * (BN / 64) + j;
      const u16* src = W + (size_t)(nt * BN + chunk * 16 + sr) * K + (k0 + sc);
      __builtin_amdgcn_global_load_lds(
          (const __attribute__((address_space(1))) void*)src,
          (__attribute__((address_space(3))) void*)(Bs + chunk * 512), 16, 0, 0);
    }
    __syncthreads();   // compiler emits vmcnt(0) drain before s_barrier

    const int row = lane & 15, kq = (lane >> 4) * 8;
    bf16x8 af[FM], bfr[4];
    #pragma unroll
    for (int i = 0; i < FM; i++) af[i] = *(const bf16x8*)&As[(wm + i * 16 + row) * BK + kq];
    #pragma unroll
    for (int j = 0; j < 4; j++)  bfr[j] = *(const bf16x8*)&Bs[(wn + j * 16 + row) * BK + kq];
    #pragma unroll
    for (int i = 0; i < FM; i++)
      #pragma unroll
      for (int j = 0; j < 4; j++)
        acc[i][j] = __builtin_amdgcn_mfma_f32_16x16x32_bf16(af[i], bfr[j], acc[i][j], 0, 0, 0);
    __syncthreads();
  }

  const int rb4 = (lane >> 4) * 4, col = lane & 15;
  #pragma unroll
  for (int i = 0; i < FM; i++) {
    #pragma unroll
    for (int j = 0; j < 4; j++) {
      #pragma unroll
      for (int r = 0; r < 4; r++) {
        const int m = mt * BM + wm + i * 16 + rb4 + r;
        const int n = nt * BN + wn + j * 16 + col;
        const float v = acc[i][j][r];
        if (EPI == 0) {
          if (n < DI) ((u16*)o0)[(size_t)m * DI + n] = f2bf(v);
          else        ((u16*)out1)[(size_t)m * DI + (n - DI)] = f2bf(silu_f(v));
        } else if (EPI == 1) {
          ((u16*)o0)[(size_t)m * ldo + n] = f2bf(v);
        } else if (EPI == 2) {
          ((u16*)o0)[(size_t)m * ldo + n] = f2bf(softplus_f(v + bi[n]));
        } else {
          ((float*)o0)[(size_t)m * ldo + n] = v;
        }
      }
    }
  }
}

// ---------------------------------------------------------------------------
// Depthwise causal conv(4) + bias + silu, BOTH directions in one ascending
// pass: window (c0,c1,c2,cn) = x[l-3..l] gives
//   xf[l]           = bf + wf0*c0 + wf1*c1 + wf2*c2 + wf3*cn
//   xr[SEQ-1-(l-3)] = br + wr3*c0 + wr2*c1 + wr1*c2 + wr0*cn
// Each thread: 8 contiguous channels (16B vector loads/stores), CLT steps.
// grid: (SEQ/(2*CLT), B_SZ), 256 thr = 128 channel-octets x 2 l-subtiles.
// ---------------------------------------------------------------------------
__global__ __launch_bounds__(256) void conv2_k(
    const u16* __restrict__ xpre,
    const float* __restrict__ wf, const float* __restrict__ bf_,
    const float* __restrict__ wr, const float* __restrict__ br_,
    u16* __restrict__ xf, u16* __restrict__ xr)
{
  const int tid  = threadIdx.x;
  const int et   = tid & 127;          // channel octet index
  const int lsub = tid >> 7;           // 0..1
  const int e0 = et * 8;
  const int b  = blockIdx.y;
  const int l0 = (blockIdx.x * 2 + lsub) * CLT;
  const size_t base = (size_t)b * SEQ * DI + e0;

  float4 wf4[8], wr4[8];
  float  bfv[8], brv[8];
  #pragma unroll
  for (int j = 0; j < 8; j++) {
    wf4[j] = *(const float4*)(wf + (e0 + j) * 4);
    wr4[j] = *(const float4*)(wr + (e0 + j) * 4);
    bfv[j] = bf_[e0 + j];
    brv[j] = br_[e0 + j];
  }

  float c0[8], c1[8], c2[8];
  auto loadv = [&](int l, float* dst) {
    if (l < 0 || l >= SEQ) {
      #pragma unroll
      for (int j = 0; j < 8; j++) dst[j] = 0.f;
      return;
    }
    union { uint4 v; u16 s[8]; } t;
    t.v = *(const uint4*)(xpre + base + (size_t)l * DI);
    #pragma unroll
    for (int j = 0; j < 8; j++) dst[j] = bf2f(t.s[j]);
  };
  loadv(l0 - 3, c0); loadv(l0 - 2, c1); loadv(l0 - 1, c2);

  #pragma unroll
  for (int i = 0; i < CLT + 3; i++) {
    const int l = l0 + i;
    float cn[8];
    loadv(l, cn);
    if (i < CLT) {                       // forward output at l
      union { uint4 v; u16 s[8]; } o;
      #pragma unroll
      for (int j = 0; j < 8; j++) {
        const float v = bfv[j] + wf4[j].x * c0[j] + wf4[j].y * c1[j]
                               + wf4[j].z * c2[j] + wf4[j].w * cn[j];
        o.s[j] = f2bf(silu_f(v));
      }
      *(uint4*)(xf + base + (size_t)l * DI) = o.v;
    }
    if (i >= 3) {                        // reverse output for orig pos lr=l-3
      const int lr = l - 3;
      union { uint4 v; u16 s[8]; } o;
      #pragma unroll
      for (int j = 0; j < 8; j++) {
        const float v = brv[j] + wr4[j].w * c0[j] + wr4[j].z * c1[j]
                               + wr4[j].y * c2[j] + wr4[j].x * cn[j];
        o.s[j] = f2bf(silu_f(v));
      }
      *(uint4*)(xr + base + (size_t)(SEQ - 1 - lr) * DI) = o.v;
    }
    #pragma unroll
    for (int j = 0; j < 8; j++) { c0[j] = c1[j]; c1[j] = c2[j]; c2[j] = cn[j]; }
  }
}

// ---------------------------------------------------------------------------
// Scan pass A (merged dirs): per (dir,b,chunk,e) chunk-local scan from h=0.
// PRE: delta precomputed (bf16). Otherwise on-the-fly (4-acc dot + softplus).
// grid: (4 e-blocks, nchunk, 4=dir*2+b)
// ---------------------------------------------------------------------------
template<bool PRE>
__global__ __launch_bounds__(256) void scanA_k(
    const u16* __restrict__ xdblf_, const u16* __restrict__ xdblr_,
    const u16* __restrict__ xf_,    const u16* __restrict__ xr_,
    const float* __restrict__ Alf,  const float* __restrict__ Alr,
    const float* __restrict__ dtwf, const float* __restrict__ dtwr,
    const float* __restrict__ dtbf, const float* __restrict__ dtbr,
    const u16* __restrict__ df_,    const u16* __restrict__ dr_,
    float* __restrict__ sumdP, float* __restrict__ bP, int ct)
{
  const int e = blockIdx.x * 256 + threadIdx.x;
  const int c = blockIdx.y;
  const int dir = blockIdx.z >> 1, b = blockIdx.z & 1;
  const u16* xdbl = dir ? xdblr_ : xdblf_;
  const u16* x    = dir ? xr_ : xf_;
  const float* Al = dir ? Alr : Alf;
  const u16* dpre = dir ? dr_ : df_;

  float A2[DS], h[DS], dw[DTR];
  #pragma unroll
  for (int n = 0; n < DS; n++) { A2[n] = -__expf(Al[e * DS + n]) * LOG2E; h[n] = 0.f; }
  const float A20 = A2[0];
  bool structured = true;
  #pragma unroll
  for (int n = 1; n < DS; n++)
    structured = structured && (fabsf(A2[n] - (float)(n + 1) * A20) <= 1e-3f * fabsf(A2[n]));

  float bias = 0.f;
  if (!PRE) {
    const float* dtw = dir ? dtwr : dtwf;
    #pragma unroll
    for (int r = 0; r < DTR; r += 4) {
      const float4 v = *(const float4*)(dtw + e * DTR + r);
      dw[r] = v.x; dw[r+1] = v.y; dw[r+2] = v.z; dw[r+3] = v.w;
    }
    bias = (dir ? dtbr : dtbf)[e];
  }

  float sumd = 0.f;
  const size_t m0 = (size_t)b * SEQ + (size_t)c * ct;

  auto core = [&](auto sc) {
    constexpr bool S = decltype(sc)::value;
    for (int t = 0; t < ct; t++) {
      const size_t m = m0 + t;
      float d;
      if (PRE) {
        d = bf2f(dpre[m * DI + e]);
      } else {
        union { uint4 v[4]; u16 s[32]; } DT;
        #pragma unroll
        for (int q = 0; q < 4; q++) DT.v[q] = ((const uint4*)(xdbl + m * 64))[q];
        float a0 = 0.f, a1 = 0.f, a2 = 0.f, a3 = 0.f;
        #pragma unroll
        for (int r = 0; r < DTR; r += 4) {
          a0 += bf2f(DT.s[r+0]) * dw[r+0];
          a1 += bf2f(DT.s[r+1]) * dw[r+1];
          a2 += bf2f(DT.s[r+2]) * dw[r+2];
          a3 += bf2f(DT.s[r+3]) * dw[r+3];
        }
        d = softplus_f(((a0 + a1) + (a2 + a3)) + bias);
      }
      const float xv  = bf2f(x[m * DI + e]);
      const float dbx = d * xv;
      sumd += d;
      union { uint4 v[2]; u16 s[16]; } Bv;
      Bv.v[0] = ((const uint4*)(xdbl + m * 64 + 32))[0];
      Bv.v[1] = ((const uint4*)(xdbl + m * 64 + 32))[1];
      float dAv[DS];
      dA_calc<S>(d, A2, A20, dAv);
      #pragma unroll
      for (int n = 0; n < DS; n++)
        h[n] = dAv[n] * h[n] + dbx * bf2f(Bv.s[n]);
    }
  };
  if (structured) core(TrueT{}); else core(FalseT{});

  const int g = (dir * 2 + b) * DI + e;
  const size_t cb = (size_t)c * NCHAN + (size_t)g * DS;
  #pragma unroll
  for (int n = 0; n < DS; n++) bP[cb + n] = h[n];
  sumdP[(size_t)c * NG + g] = sumd;
}

// Scan pass B: cross-chunk scan, in place (bP becomes h_in per chunk).
__global__ __launch_bounds__(256) void scanB_k(
    const float* __restrict__ sumdP, float* __restrict__ bP,
    const float* __restrict__ Alog_f, const float* __restrict__ Alog_r, int nchunk)
{
  const int ch = blockIdx.x * 256 + threadIdx.x;   // 0..65535
  const int g = ch >> 4, n = ch & 15;
  const int dir = g >> 11, e = g & (DI - 1);
  const float* Al = dir ? Alog_r : Alog_f;
  const float A2 = -__expf(Al[e * DS + n]) * LOG2E;
  float h = 0.f;
  for (int c = 0; c < nchunk; c++) {
    const float a = exp2f(A2 * sumdP[(size_t)c * NG + g]);
    const size_t i = (size_t)c * NCHAN + ch;
    const float bb = bP[i];
    bP[i] = h;              // h_in for chunk c
    h = a * h + bb;
  }
}

// ---------------------------------------------------------------------------
// Scan pass C: replay chunk from h_in, emit y (+ x*D).
// MODE 0: merged dirs (z=dir*2+b). dir0 -> yf[m] (in place over x_f);
//         dir1 -> yr[mo] (mo = flipped). No sz/Yf read.
// MODE 1: legacy dir0 only (z=b): yf[m] = y + x*D
// MODE 2: legacy dir1 combine (z=b): yr[mo] = (yf[mo] + y + x*D) * sz[mo]
// ---------------------------------------------------------------------------
template<bool PRE, int MODE>
__global__ __launch_bounds__(256) void scanC_k(
    const u16* __restrict__ xdblf_, const u16* __restrict__ xdblr_,
    const u16* __restrict__ xf_,    const u16* __restrict__ xr_,
    const float* __restrict__ Alf,  const float* __restrict__ Alr,
    const float* __restrict__ dtwf, const float* __restrict__ dtwr,
    const float* __restrict__ dtbf, const float* __restrict__ dtbr,
    const u16* __restrict__ df_,    const u16* __restrict__ dr_,
    const float* __restrict__ Dskf, const float* __restrict__ Dskr,
    const float* __restrict__ hin,
    u16* __restrict__ yf, u16* __restrict__ yr,
    const u16* __restrict__ szp, int ct)
{
  const int e = blockIdx.x * 256 + threadIdx.x;
  const int c = blockIdx.y;
  int dir, b;
  if (MODE == 0) { dir = blockIdx.z >> 1; b = blockIdx.z & 1; }
  else           { dir = (MODE == 2);     b = blockIdx.z; }
  const u16* xdbl = dir ? xdblr_ : xdblf_;
  const u16* x    = dir ? xr_ : xf_;
  const float* Al = dir ? Alr : Alf;
  const u16* dpre = dir ? dr_ : df_;
  const float dskip = (dir ? Dskr : Dskf)[e];

  float A2[DS], h[DS], dw[DTR];
  #pragma unroll
  for (int n = 0; n < DS; n++) A2[n] = -__expf(Al[e * DS + n]) * LOG2E;
  const float A20 = A2[0];
  bool structured = true;
  #pragma unroll
  for (int n = 1; n < DS; n++)
    structured = structured && (fabsf(A2[n] - (float)(n + 1) * A20) <= 1e-3f * fabsf(A2[n]));

  float bias = 0.f;
  if (!PRE) {
    const float* dtw = dir ? dtwr : dtwf;
    #pragma unroll
    for (int r = 0; r < DTR; r += 4) {
      const float4 v = *(const float4*)(dtw + e * DTR + r);
      dw[r] = v.x; dw[r+1] = v.y; dw[r+2] = v.z; dw[r+3] = v.w;
    }
    bias = (dir ? dtbr : dtbf)[e];
  }

  const int g = (dir * 2 + b) * DI + e;
  const size_t cb = (size_t)c * NCHAN + (size_t)g * DS;
  #pragma unroll
  for (int n = 0; n < DS; n++) h[n] = hin[cb + n];
  const size_t m0 = (size_t)b * SEQ + (size_t)c * ct;

  auto core = [&](auto sc) {
    constexpr bool S = decltype(sc)::value;
    for (int t = 0; t < ct; t++) {
      const size_t m = m0 + t;
      float d;
      union { uint4 v[4]; u16 s[32]; } BC;
      #pragma unroll
      for (int q = 0; q < 4; q++) BC.v[q] = ((const uint4*)(xdbl + m * 64 + 32))[q];
      if (PRE) {
        d = bf2f(dpre[m * DI + e]);
      } else {
        union { uint4 v[4]; u16 s[32]; } DT;
        #pragma unroll
        for (int q = 0; q < 4; q++) DT.v[q] = ((const uint4*)(xdbl + m * 64))[q];
        float a0 = 0.f, a1 = 0.f, a2 = 0.f, a3 = 0.f;
        #pragma unroll
        for (int r = 0; r < DTR; r += 4) {
          a0 += bf2f(DT.s[r+0]) * dw[r+0];
          a1 += bf2f(DT.s[r+1]) * dw[r+1];
          a2 += bf2f(DT.s[r+2]) * dw[r+2];
          a3 += bf2f(DT.s[r+3]) * dw[r+3];
        }
        d = softplus_f(((a0 + a1) + (a2 + a3)) + bias);
      }
      const float xv  = bf2f(x[m * DI + e]);
      const float dbx = d * xv;
      float dAv[DS];
      dA_calc<S>(d, A2, A20, dAv);
      float y = 0.f;
      #pragma unroll
      for (int n = 0; n < DS; n++) {
        h[n] = dAv[n] * h[n] + dbx * bf2f(BC.s[n]);
        y += h[n] * bf2f(BC.s[16 + n]);
      }
      const float yout = y + xv * dskip;
      if (MODE == 0) {
        if (dir == 0) {
          yf[m * DI + e] = f2bf(yout);
        } else {
          const size_t mo = (size_t)b * SEQ + (SEQ - 1 - (c * ct + t));
          yr[mo * DI + e] = f2bf(yout);
        }
      } else if (MODE == 1) {
        yf[m * DI + e] = f2bf(yout);
      } else {
        const size_t mo = (size_t)b * SEQ + (SEQ - 1 - (c * ct + t));
        const size_t moi = mo * DI + e;
        yr[moi] = f2bf((bf2f(yf[moi]) + yout) * bf2f(szp[moi]));
      }
    }
  };
  if (structured) core(TrueT{}); else core(FalseT{});
}

// Elementwise combine (big path): yf = (yf + yr) * sz, 8 bf16 per thread.
__global__ __launch_bounds__(256) void comb_k(
    u16* __restrict__ yfp, const u16* __restrict__ yrp, const u16* __restrict__ szp)
{
  const size_t i = ((size_t)blockIdx.x * 256 + threadIdx.x) * 8;
  union { uint4 v; u16 s[8]; } A, Bq, S, O;
  A.v  = *(const uint4*)(yfp + i);
  Bq.v = *(const uint4*)(yrp + i);
  S.v  = *(const uint4*)(szp + i);
  #pragma unroll
  for (int j = 0; j < 8; j++)
    O.s[j] = f2bf((bf2f(A.s[j]) + bf2f(Bq.s[j])) * bf2f(S.s[j]));
  *(uint4*)(yfp + i) = O.v;
}

// ---------------------------------------------------------------------------
extern "C" void kernel_launch(void* const* d_in, const int* in_sizes, int n_in,
                              void* d_out, int out_size, void* d_ws, size_t ws_size,
                              hipStream_t stream)
{
  (void)in_sizes; (void)n_in; (void)out_size;
  const float* u      = (const float*)d_in[0];
  const float* in_w   = (const float*)d_in[1];
  const float* out_w  = (const float*)d_in[2];
  const float* cw_f   = (const float*)d_in[3];
  const float* cb_f   = (const float*)d_in[4];
  const float* xw_f   = (const float*)d_in[5];
  const float* dtw_f  = (const float*)d_in[6];
  const float* dtb_f  = (const float*)d_in[7];
  const float* Alog_f = (const float*)d_in[8];
  const float* D_f    = (const float*)d_in[9];
  const float* cw_r   = (const float*)d_in[10];
  const float* cb_r   = (const float*)d_in[11];
  const float* xw_r   = (const float*)d_in[12];
  const float* dtw_r  = (const float*)d_in[13];
  const float* dtb_r  = (const float*)d_in[14];
  const float* Alog_r = (const float*)d_in[15];
  const float* D_r    = (const float*)d_in[16];

  const size_t mexe = (size_t)M_TOT * DI;          // 16.78M elements
  // big layout: ubf(=df) + xpre + xf + xr + xdbl*2 + wbf + sumdP128 + bP128 + dr ~= 215 MB
  const size_t need_big =
      5 * (mexe * 2) + 2 * ((size_t)M_TOT * 64 * 2) + (size_t)WU_TOT * 16 +
      (size_t)128 * NG * 4 + (size_t)128 * NCHAN * 4 + 32 * 256;
  const bool big = (ws_size >= need_big);
  const int nchunk = big ? 128 : 64;
  const int ct = SEQ / nchunk;

  char* ws = (char*)d_ws;
  size_t off = 0;
  auto alloc = [&](size_t bytes) -> void* {
    void* p = ws + off;
    off += (bytes + 255) & ~(size_t)255;
    return p;
  };
  u16*   ubf   = (u16*)alloc(mexe * 2);            // bf16 u (8.39M used); dead after in_proj -> df
  u16*   xpre  = (u16*)alloc(mexe * 2);            // dead after conv -> yr
  u16*   xf    = (u16*)alloc(mexe * 2);            // x_f; in-place y_f
  u16*   xr    = (u16*)alloc(mexe * 2);
  u16*   xdblf = (u16*)alloc((size_t)M_TOT * 64 * 2);
  u16*   xdblr = (u16*)alloc((size_t)M_TOT * 64 * 2);
  u16*   wbf   = (u16*)alloc((size_t)WU_TOT * 16); // bf16 weight arena
  float* sumdP = (float*)alloc((size_t)nchunk * NG * 4);
  float* bP    = (float*)alloc((size_t)nchunk * NCHAN * 4);
  u16*   dr    = big ? (u16*)alloc(mexe * 2) : nullptr;
  u16*   df    = ubf;                              // alias (u dead after in_proj)
  u16*   szb   = (u16*)d_out;                      // silu(z) in d_out (dead before out_proj)

  // weight arena sub-pointers (units of 8 elems = 16 B)
  u16* winb  = wbf;
  u16* xwbf  = wbf + (size_t)WU_INW * 8;
  u16* xwbr  = xwbf + (size_t)WU_XW * 8;
  u16* dtwbf = xwbr + (size_t)WU_XW * 8;
  u16* dtwbr = dtwbf + (size_t)WU_DTW * 8;
  u16* outwb = dtwbr + (size_t)WU_DTW * 8;

  dim3 blk(256);
  // 0) convert u + weights to bf16.  u has M_TOT*DM = 8.39M elems -> 4096 blocks.
  cvt_k<<<dim3((unsigned)((size_t)M_TOT * DM / 8 / 256)), blk, 0, stream>>>(u, ubf);
  cvtw_k<<<dim3(WU_TOT / 256), blk, 0, stream>>>(in_w, xw_f, xw_r, dtw_f, dtw_r, out_w, wbf);
  // 1) in_proj: xz = u @ in_w^T ; split -> xpre(bf16), sz=silu(z) in d_out
  gemm_k<128, 0, false><<<dim3(128, 16), blk, 0, stream>>>(
      ubf, nullptr, DM, winb, nullptr, DM, xpre, nullptr, szb, nullptr, nullptr, 0);
  // 2) depthwise conv + silu, both dirs in one pass
  conv2_k<<<dim3(SEQ / (2 * CLT), B_SZ), blk, 0, stream>>>(
      xpre, cw_f, cb_f, cw_r, cb_r, xf, xr);
  // 3) xproj (dual): xdbl = x @ xproj_w^T
  gemm_k<64, 1, true><<<dim3(128, 1, 2), blk, 0, stream>>>(
      xf, xr, DI, xwbf, xwbr, DI, xdblf, xdblr, nullptr, nullptr, nullptr, 64);

  if (big) {
    // 4) delta (dual): softplus(xdbl[:, :32] @ dtw^T + dtb) -> bf16 (df aliases ubf)
    gemm_k<128, 2, true><<<dim3(128, 8, 2), blk, 0, stream>>>(
        xdblf, xdblr, 64, dtwbf, dtwbr, DTR, df, dr, nullptr, dtb_f, dtb_r, DI);
    // 5) scan
    scanA_k<true><<<dim3(4, nchunk, 4), blk, 0, stream>>>(
        xdblf, xdblr, xf, xr, Alog_f, Alog_r, dtw_f, dtw_r, dtb_f, dtb_r,
        df, dr, sumdP, bP, ct);
    scanB_k<<<dim3(NCHAN / 256), blk, 0, stream>>>(sumdP, bP, Alog_f, Alog_r, nchunk);
    scanC_k<true, 0><<<dim3(4, nchunk, 4), blk, 0, stream>>>(
        xdblf, xdblr, xf, xr, Alog_f, Alog_r, dtw_f, dtw_r, dtb_f, dtb_r,
        df, dr, D_f, D_r, bP, xf, xpre, nullptr, ct);
    // 6) combine: yf = (yf + yr) * silu(z)
    comb_k<<<dim3((unsigned)(mexe / 8 / 256)), blk, 0, stream>>>(xf, xpre, szb);
    // 7) out_proj from xf
    gemm_k<128, 3, false><<<dim3(128, 4), blk, 0, stream>>>(
        xf, nullptr, DI, outwb, nullptr, DI, d_out, nullptr, nullptr, nullptr, nullptr, DM);
  } else {
    // legacy (low-ws) path: on-the-fly delta, serialized scanC
    scanA_k<false><<<dim3(4, nchunk, 4), blk, 0, stream>>>(
        xdblf, xdblr, xf, xr, Alog_f, Alog_r, dtw_f, dtw_r, dtb_f, dtb_r,
        nullptr, nullptr, sumdP, bP, ct);
    scanB_k<<<dim3(NCHAN / 256), blk, 0, stream>>>(sumdP, bP, Alog_f, Alog_r, nchunk);
    scanC_k<false, 1><<<dim3(4, nchunk, 2), blk, 0, stream>>>(
        xdblf, xdblr, xf, xr, Alog_f, Alog_r, dtw_f, dtw_r, dtb_f, dtb_r,
        nullptr, nullptr, D_f, D_r, bP, xf, nullptr, nullptr, ct);
    scanC_k<false, 2><<<dim3(4, nchunk, 2), blk, 0, stream>>>(
        xdblf, xdblr, xf, xr, Alog_f, Alog_r, dtw_f, dtw_r, dtb_f, dtb_r,
        nullptr, nullptr, D_f, D_r, bP, xf, xpre, szb, ct);
    gemm_k<128, 3, false><<<dim3(128, 4), blk, 0, stream>>>(
        xpre, nullptr, DI, outwb, nullptr, DI, d_out, nullptr, nullptr, nullptr, nullptr, DM);
  }
}